// Round 1
// baseline (151.771 us; speedup 1.0000x reference)
//
#include <hip/hip_runtime.h>
#include <hip/hip_bf16.h>
#include <math.h>

#define DEV static __device__ __forceinline__

typedef unsigned short u16;
typedef __attribute__((ext_vector_type(4))) float f32x4;
typedef __attribute__((ext_vector_type(8))) __bf16 bf16x8;
typedef __attribute__((ext_vector_type(4))) u16 u16x4;

// float -> bf16 bits, round-to-nearest-even
DEV u16 f2bf(float f) {
  unsigned u = __float_as_uint(f);
  u += 0x7fffu + ((u >> 16) & 1u);
  return (u16)(u >> 16);
}

DEV void gl2lds16(const void* g, void* l) {
  __builtin_amdgcn_global_load_lds(
      (const __attribute__((address_space(1))) void*)g,
      (__attribute__((address_space(3))) void*)l, 16, 0, 0);
}

// Stage RPW rows (per wave) x 64 bf16 cols from global (row stride = gstride elems)
// into linear LDS [rows][64]. global_load_lds writes LDS linearly (base + lane*16B),
// so the XOR bank-swizzle is applied to the GLOBAL source slot (rule: both-sides-
// or-neither). LDS[row][slot] <- global[row][slot ^ (row&7)].
template<int RPW>
DEV void stage_rows(const u16* __restrict__ g, int gstride, u16* lds, int wave, int lane) {
  const int r_in = lane >> 3, slot = lane & 7;
  const int base_row = wave * RPW;
#pragma unroll
  for (int i = 0; i < RPW / 8; ++i) {
    const int row = base_row + i * 8 + r_in;
    const int sslot = slot ^ (row & 7);
    gl2lds16(g + (size_t)row * gstride + sslot * 8,
             lds + (size_t)(base_row + i * 8) * 64);
  }
}

// Read one 16x16x32 A/B fragment (8 bf16, contiguous k) from the swizzled tile.
// kslot indexes 8-element k-chunks: k = kslot*8 .. +7.
DEV bf16x8 frag_read(const u16* lds, int row, int kslot) {
  const int slot = kslot ^ (row & 7);
  return *(const bf16x8*)(lds + row * 64 + slot * 8);
}

DEV f32x4 mfma16(bf16x8 a, bf16x8 b, f32x4 c) {
  return __builtin_amdgcn_mfma_f32_16x16x32_bf16(a, b, c, 0, 0, 0);
}

// ---------------------------------------------------------------------------
// Weights fp32 -> bf16. grid (256, 4), block 256. dst: [Wq][Wk][Wv][Wo].
__global__ __launch_bounds__(256) void convert_w(
    const float* __restrict__ w0, const float* __restrict__ w1,
    const float* __restrict__ w2, const float* __restrict__ w3,
    u16* __restrict__ dst) {
  const float* src = (blockIdx.y == 0) ? w0 : (blockIdx.y == 1) ? w1
                   : (blockIdx.y == 2) ? w2 : w3;
  const size_t base = (size_t)blockIdx.y * 262144;
  const int i = (blockIdx.x * 256 + threadIdx.x) * 4;
  f32x4 v = *(const f32x4*)(src + i);
  u16x4 o;
  o.x = f2bf(v.x); o.y = f2bf(v.y); o.z = f2bf(v.z); o.w = f2bf(v.w);
  *(u16x4*)(dst + base + i) = o;
}

// ---------------------------------------------------------------------------
// x (B,C,H,W) -> Xp bf16 (B*S, D) and resid fp32, adding 2D positional encoding.
// grid (32 s-tiles, 16 c-tiles, 8 b), block 256. LDS 32x33 transpose tile.
__global__ __launch_bounds__(256) void prep_x(
    const float* __restrict__ x, u16* __restrict__ Xp, float* __restrict__ resid) {
  __shared__ float tile[32][33];
  const int b = blockIdx.z, c0 = blockIdx.y * 32, s0 = blockIdx.x * 32;
  const int t = threadIdx.x;
  const int cf = t >> 5, sf = t & 31;
#pragma unroll
  for (int i = 0; i < 4; ++i) {
    const int c = c0 + cf + i * 8;
    tile[cf + i * 8][sf] = x[((size_t)b * 512 + c) * 1024 + s0 + sf];
  }
  __syncthreads();
  const int cl = t & 31, sl = t >> 5;
  const int cg = c0 + cl;
  const int j = cg >> 2;
  // div[j] = 10000^(-j/256) = exp(-j*ln(10000)/256)
  const float dv = expf((float)j * (-9.210340371976184f / 256.0f));
#pragma unroll
  for (int i = 0; i < 4; ++i) {
    const int s = s0 + sl + i * 8;
    const float pos = (cg & 2) ? (float)(s & 31) : (float)(s >> 5); // pos_w : pos_h
    const float arg = pos * dv;
    const float pe = (cg & 1) ? cosf(arg) : sinf(arg);
    const float v = tile[cl][sl + i * 8] + pe;
    const size_t r = (size_t)b * 1024 + s;
    Xp[r * 512 + cg] = f2bf(v);
    resid[r * 512 + cg] = v;
  }
}

// ---------------------------------------------------------------------------
// C[M,N] = A[M,K] @ Bt[N,K]^T, bf16 in, fp32 accum. 128x128 tile, BK=64,
// 4 waves in 2x2, each wave a 64x64 sub-tile of 4x4 16x16 fragments.
// EPI=0: bf16 out, scaled by alpha. EPI=1: fp32 out + bias[col] + resid[row,col].
template<int EPI>
__global__ __launch_bounds__(256) void gemm_bt(
    const u16* __restrict__ A, const u16* __restrict__ Bt, void* __restrict__ Cout,
    int M, int N, int K, float alpha,
    const float* __restrict__ bias, const float* __restrict__ resid) {
  __shared__ __align__(16) u16 As[128 * 64];
  __shared__ __align__(16) u16 Bs[128 * 64];
  const int t = threadIdx.x, lane = t & 63, wave = t >> 6;
  const int bn0 = blockIdx.x * 128, bm0 = blockIdx.y * 128;
  const int wr = wave >> 1, wc = wave & 1;
  const u16* Ag = A + (size_t)bm0 * K;
  const u16* Bg = Bt + (size_t)bn0 * K;
  f32x4 acc[4][4] = {};
  for (int kt = 0; kt < K; kt += 64) {
    __syncthreads();
    stage_rows<32>(Ag + kt, K, As, wave, lane);
    stage_rows<32>(Bg + kt, K, Bs, wave, lane);
    __syncthreads();
#pragma unroll
    for (int ks = 0; ks < 2; ++ks) {
      bf16x8 af[4], bfr[4];
#pragma unroll
      for (int m = 0; m < 4; ++m)
        af[m] = frag_read(As, wr * 64 + m * 16 + (lane & 15), ks * 4 + (lane >> 4));
#pragma unroll
      for (int n = 0; n < 4; ++n)
        bfr[n] = frag_read(Bs, wc * 64 + n * 16 + (lane & 15), ks * 4 + (lane >> 4));
#pragma unroll
      for (int m = 0; m < 4; ++m)
#pragma unroll
        for (int n = 0; n < 4; ++n)
          acc[m][n] = mfma16(af[m], bfr[n], acc[m][n]);
    }
  }
  // C/D layout: col = lane&15, row = (lane>>4)*4 + reg  [m89-verified]
  const int cl = lane & 15, rg = (lane >> 4) * 4;
#pragma unroll
  for (int m = 0; m < 4; ++m)
#pragma unroll
    for (int n = 0; n < 4; ++n) {
      const int col = bn0 + wc * 64 + n * 16 + cl;
#pragma unroll
      for (int r = 0; r < 4; ++r) {
        const int row = bm0 + wr * 64 + m * 16 + rg + r;
        const float v = acc[m][n][r];
        if (EPI == 0) {
          ((u16*)Cout)[(size_t)row * N + col] = f2bf(v * alpha);
        } else {
          ((float*)Cout)[(size_t)row * N + col] =
              v + bias[col] + resid[(size_t)row * N + col];
        }
      }
    }
}

// ---------------------------------------------------------------------------
// Flash attention. grid (8 q-tiles, 8 heads, 8 batch), 256 threads = 4 waves.
// Each wave owns 32 q-rows. KV tiles of 64. Q/K row-major (8192,512) slices;
// Vt is V^T (512, 8192) so PV gets a natural Bt operand.
__global__ __launch_bounds__(256) void attn(
    const u16* __restrict__ Qb, const u16* __restrict__ Kb,
    const u16* __restrict__ Vt, u16* __restrict__ Ob) {
  __shared__ __align__(16) u16 Qs[128 * 64];
  __shared__ __align__(16) u16 Ks[64 * 64];
  __shared__ __align__(16) u16 Vs[64 * 64];
  __shared__ __align__(16) u16 Ps[4][32 * 64];
  const int t = threadIdx.x, lane = t & 63, wave = t >> 6;
  const int qt = blockIdx.x, h = blockIdx.y, b = blockIdx.z;
  stage_rows<32>(Qb + ((size_t)b * 1024 + qt * 128) * 512 + h * 64, 512, Qs, wave, lane);
  __syncthreads();
  bf16x8 aq[2][2];
#pragma unroll
  for (int m = 0; m < 2; ++m)
#pragma unroll
    for (int ks = 0; ks < 2; ++ks)
      aq[m][ks] = frag_read(Qs, wave * 32 + m * 16 + (lane & 15), ks * 4 + (lane >> 4));
  f32x4 o[2][4] = {};
  float mst[2][4], lst[2][4];
#pragma unroll
  for (int m = 0; m < 2; ++m)
#pragma unroll
    for (int r = 0; r < 4; ++r) { mst[m][r] = -1e30f; lst[m][r] = 0.f; }
  u16* Pw = &Ps[wave][0];
  for (int kv = 0; kv < 16; ++kv) {
    __syncthreads();
    stage_rows<16>(Kb + ((size_t)b * 1024 + kv * 64) * 512 + h * 64, 512, Ks, wave, lane);
    stage_rows<16>(Vt + (size_t)(h * 64) * 8192 + (size_t)b * 1024 + kv * 64, 8192, Vs, wave, lane);
    __syncthreads();
    // S = Q @ K^T  (scale 1/sqrt(dk) pre-folded into Q)
    f32x4 s[2][4] = {};
#pragma unroll
    for (int ks = 0; ks < 2; ++ks) {
      bf16x8 bk[4];
#pragma unroll
      for (int n = 0; n < 4; ++n)
        bk[n] = frag_read(Ks, n * 16 + (lane & 15), ks * 4 + (lane >> 4));
#pragma unroll
      for (int m = 0; m < 2; ++m)
#pragma unroll
        for (int n = 0; n < 4; ++n)
          s[m][n] = mfma16(aq[m][ks], bk[n], s[m][n]);
    }
    // online softmax: rows live in 16-lane groups (col = lane&15)
    {
      const int cl = lane & 15, rg = (lane >> 4) * 4;
#pragma unroll
      for (int m = 0; m < 2; ++m)
#pragma unroll
        for (int r = 0; r < 4; ++r) {
          float mx = fmaxf(fmaxf(s[m][0][r], s[m][1][r]), fmaxf(s[m][2][r], s[m][3][r]));
#pragma unroll
          for (int off = 8; off >= 1; off >>= 1) mx = fmaxf(mx, __shfl_xor(mx, off));
          const float mn = fmaxf(mst[m][r], mx);
          const float sc = __expf(mst[m][r] - mn);
          mst[m][r] = mn;
          float rs = 0.f;
#pragma unroll
          for (int n = 0; n < 4; ++n) {
            const float p = __expf(s[m][n][r] - mn);
            s[m][n][r] = p;
            rs += p;
          }
#pragma unroll
          for (int off = 8; off >= 1; off >>= 1) rs += __shfl_xor(rs, off);
          lst[m][r] = lst[m][r] * sc + rs;
#pragma unroll
          for (int n = 0; n < 4; ++n) o[m][n][r] *= sc;
          // stage P row to wave-private LDS (bf16, same XOR swizzle as frag_read)
          const int row = m * 16 + rg + r;
          const int rw = row & 7;
#pragma unroll
          for (int n = 0; n < 4; ++n) {
            const int colc = n * 16 + cl;
            const int swz = (colc & 7) | ((((colc >> 3) ^ rw)) << 3);
            Pw[row * 64 + swz] = f2bf(s[m][n][r]);
          }
        }
    }
    // O += P @ V   (Bt = Vs, rows = d, cols = kv)
#pragma unroll
    for (int ks = 0; ks < 2; ++ks) {
      bf16x8 pa[2], bv[4];
#pragma unroll
      for (int m = 0; m < 2; ++m)
        pa[m] = frag_read(Pw, m * 16 + (lane & 15), ks * 4 + (lane >> 4));
#pragma unroll
      for (int n = 0; n < 4; ++n)
        bv[n] = frag_read(Vs, n * 16 + (lane & 15), ks * 4 + (lane >> 4));
#pragma unroll
      for (int m = 0; m < 2; ++m)
#pragma unroll
        for (int n = 0; n < 4; ++n)
          o[m][n] = mfma16(pa[m], bv[n], o[m][n]);
    }
  }
  const int cl2 = lane & 15, rg2 = (lane >> 4) * 4;
#pragma unroll
  for (int m = 0; m < 2; ++m)
#pragma unroll
    for (int r = 0; r < 4; ++r) {
      const float inv = 1.f / lst[m][r];
      const size_t row = (size_t)b * 1024 + qt * 128 + wave * 32 + m * 16 + rg2 + r;
#pragma unroll
      for (int n = 0; n < 4; ++n) {
        const int col = h * 64 + n * 16 + cl2;
        Ob[row * 512 + col] = f2bf(o[m][n][r] * inv);
      }
    }
}

// ---------------------------------------------------------------------------
// LayerNorm over d=512 + transpose back to (B,C,H,W). grid (32 s-tiles, 8 b).
__global__ __launch_bounds__(256) void ln_out(
    const float* __restrict__ ypre, const float* __restrict__ gamma,
    const float* __restrict__ beta, float* __restrict__ out) {
  __shared__ float stats[32][2];
  __shared__ float tile[32][33];
  const int b = blockIdx.y, s0 = blockIdx.x * 32;
  const int t = threadIdx.x, lane = t & 63, wave = t >> 6;
  // pass 1: per-row mean / rstd (each wave handles 8 rows)
  for (int i = 0; i < 8; ++i) {
    const int sl = wave * 8 + i;
    const float* row = ypre + ((size_t)b * 1024 + s0 + sl) * 512;
    float sum = 0.f, sq = 0.f;
#pragma unroll
    for (int k = 0; k < 8; ++k) {
      const float v = row[lane + 64 * k];
      sum += v; sq += v * v;
    }
#pragma unroll
    for (int off = 32; off >= 1; off >>= 1) {
      sum += __shfl_xor(sum, off);
      sq  += __shfl_xor(sq, off);
    }
    if (lane == 0) {
      const float mean = sum * (1.f / 512.f);
      const float var = sq * (1.f / 512.f) - mean * mean;
      stats[sl][0] = mean;
      stats[sl][1] = rsqrtf(var + 1e-5f);
    }
  }
  __syncthreads();
  // pass 2: normalize + transposed write via 32x32 LDS tile
  const int cl = t & 31, sl8 = t >> 5;
  for (int cc = 0; cc < 16; ++cc) {
    const int c0 = cc * 32;
    if (cc) __syncthreads();
#pragma unroll
    for (int i = 0; i < 4; ++i) {
      const int s = sl8 + i * 8;
      const float v = ypre[((size_t)b * 1024 + s0 + s) * 512 + c0 + cl];
      tile[s][cl] = (v - stats[s][0]) * stats[s][1];
    }
    __syncthreads();
#pragma unroll
    for (int i = 0; i < 4; ++i) {
      const int c = c0 + sl8 + i * 8;
      out[((size_t)b * 512 + c) * 1024 + s0 + cl] = tile[cl][sl8 + i * 8] * gamma[c] + beta[c];
    }
  }
}

// ---------------------------------------------------------------------------
extern "C" void kernel_launch(void* const* d_in, const int* in_sizes, int n_in,
                              void* d_out, int out_size, void* d_ws, size_t ws_size,
                              hipStream_t stream) {
  const float* x     = (const float*)d_in[0];
  const float* Wq    = (const float*)d_in[1];
  const float* Wk    = (const float*)d_in[2];
  const float* Wv    = (const float*)d_in[3];
  const float* Wo    = (const float*)d_in[4];
  const float* bo    = (const float*)d_in[5];
  const float* gamma = (const float*)d_in[6];
  const float* beta  = (const float*)d_in[7];
  char* ws = (char*)d_ws;
  const size_t MB = 1048576;
  u16*   Xp    = (u16*)(ws);             //  8 MB bf16 (8192,512): x + PE
  u16*   Wb    = (u16*)(ws + 8 * MB);    //  2 MB bf16 weights [q][k][v][o]
  float* resid = (float*)(ws + 10 * MB); // 16 MB fp32 (8192,512)
  u16*   Qb    = (u16*)(ws + 26 * MB);   //  8 MB
  u16*   Kb    = (u16*)(ws + 34 * MB);   //  8 MB
  u16*   Vtb   = (u16*)(ws + 42 * MB);   //  8 MB bf16 V^T (512, 8192)
  u16*   Ob    = (u16*)(ws + 50 * MB);   //  8 MB attention out
  float* ypre  = (float*)(ws + 26 * MB); // 16 MB, reuses dead Qb/Kb region

  convert_w<<<dim3(256, 4), 256, 0, stream>>>(Wq, Wk, Wv, Wo, Wb);
  prep_x<<<dim3(32, 16, 8), 256, 0, stream>>>(x, Xp, resid);
  // Q = (Xp @ Wq^T) / sqrt(dk);  K = Xp @ Wk^T
  gemm_bt<0><<<dim3(4, 64), 256, 0, stream>>>(Xp, Wb,           (void*)Qb, 8192, 512, 512, 0.125f, nullptr, nullptr);
  gemm_bt<0><<<dim3(4, 64), 256, 0, stream>>>(Xp, Wb + 262144,  (void*)Kb, 8192, 512, 512, 1.0f,   nullptr, nullptr);
  // V^T = Wv @ Xp^T   (so PV in attention gets a row-major Bt operand)
  gemm_bt<0><<<dim3(64, 4), 256, 0, stream>>>(Wb + 2 * 262144, Xp, (void*)Vtb, 512, 8192, 512, 1.0f, nullptr, nullptr);
  attn<<<dim3(8, 8, 8), 256, 0, stream>>>(Qb, Kb, Vtb, Ob);
  // ypre = Ob @ Wo^T + bo + resid
  gemm_bt<1><<<dim3(4, 64), 256, 0, stream>>>(Ob, Wb + 3 * 262144, (void*)ypre, 8192, 512, 512, 1.0f, bo, resid);
  ln_out<<<dim3(32, 8), 256, 0, stream>>>(ypre, gamma, beta, (float*)d_out);
}

// Round 2
// 128.989 us; speedup vs baseline: 1.1766x; 1.1766x over previous
//
#include <hip/hip_runtime.h>
#include <hip/hip_bf16.h>
#include <math.h>

#define DEV static __device__ __forceinline__

typedef unsigned short u16;
typedef unsigned int u32;
typedef __attribute__((ext_vector_type(4))) float f32x4;
typedef __attribute__((ext_vector_type(16))) float f32x16;
typedef __attribute__((ext_vector_type(8))) __bf16 bf16x8;
typedef __attribute__((ext_vector_type(4))) u16 u16x4;
typedef __attribute__((ext_vector_type(4))) u32 u32x4;

// float -> bf16 bits, round-to-nearest-even
DEV u16 f2bf(float f) {
  unsigned u = __float_as_uint(f);
  u += 0x7fffu + ((u >> 16) & 1u);
  return (u16)(u >> 16);
}

DEV u32 cvt_pk_bf16(float lo, float hi) {
  u32 r;
  asm("v_cvt_pk_bf16_f32 %0, %1, %2" : "=v"(r) : "v"(lo), "v"(hi));
  return r;
}

// v_permlane32_swap_b32: a' = {a.lo, b.lo}, b' = {a.hi, b.hi}
DEV void perm32swap(u32& a, u32& b) {
  asm("v_permlane32_swap_b32 %0, %1" : "+v"(a), "+v"(b));
}

DEV void gl2lds16(const void* g, void* l) {
  __builtin_amdgcn_global_load_lds(
      (const __attribute__((address_space(1))) void*)g,
      (__attribute__((address_space(3))) void*)l, 16, 0, 0);
}

// Stage RPW rows (per wave) x 64 bf16 cols from global (row stride = gstride elems)
// into linear LDS [rows][64]. global_load_lds writes LDS linearly (base + lane*16B),
// so the XOR bank-swizzle is applied to the GLOBAL source slot (both-sides-or-neither).
// LDS[row][slot] <- global[row][slot ^ (row&7)].
template<int RPW>
DEV void stage_rows(const u16* __restrict__ g, int gstride, u16* lds, int wave, int lane) {
  const int r_in = lane >> 3, slot = lane & 7;
  const int base_row = wave * RPW;
#pragma unroll
  for (int i = 0; i < RPW / 8; ++i) {
    const int row = base_row + i * 8 + r_in;
    const int sslot = slot ^ (row & 7);
    gl2lds16(g + (size_t)row * gstride + sslot * 8,
             lds + (size_t)(base_row + i * 8) * 64);
  }
}

// Read an 8-bf16 slot (16B) from the swizzled [rows][64] tile.
DEV bf16x8 frag_read(const u16* lds, int row, int kslot) {
  const int slot = kslot ^ (row & 7);
  return *(const bf16x8*)(lds + row * 64 + slot * 8);
}

DEV f32x4 mfma16(bf16x8 a, bf16x8 b, f32x4 c) {
  return __builtin_amdgcn_mfma_f32_16x16x32_bf16(a, b, c, 0, 0, 0);
}
DEV f32x16 mfma32(bf16x8 a, bf16x8 b, f32x16 c) {
  return __builtin_amdgcn_mfma_f32_32x32x16_bf16(a, b, c, 0, 0, 0);
}

// ---------------------------------------------------------------------------
// Weights fp32 -> bf16. grid (256, 4), block 256. dst: [Wq][Wk][Wv][Wo].
__global__ __launch_bounds__(256) void convert_w(
    const float* __restrict__ w0, const float* __restrict__ w1,
    const float* __restrict__ w2, const float* __restrict__ w3,
    u16* __restrict__ dst) {
  const float* src = (blockIdx.y == 0) ? w0 : (blockIdx.y == 1) ? w1
                   : (blockIdx.y == 2) ? w2 : w3;
  const size_t base = (size_t)blockIdx.y * 262144;
  const int i = (blockIdx.x * 256 + threadIdx.x) * 4;
  f32x4 v = *(const f32x4*)(src + i);
  u16x4 o;
  o.x = f2bf(v.x); o.y = f2bf(v.y); o.z = f2bf(v.z); o.w = f2bf(v.w);
  *(u16x4*)(dst + base + i) = o;
}

// ---------------------------------------------------------------------------
// x (B,C,H,W) -> Xp bf16 (B*S, D) and resid fp32, adding 2D positional encoding.
__global__ __launch_bounds__(256) void prep_x(
    const float* __restrict__ x, u16* __restrict__ Xp, float* __restrict__ resid) {
  __shared__ float tile[32][33];
  const int b = blockIdx.z, c0 = blockIdx.y * 32, s0 = blockIdx.x * 32;
  const int t = threadIdx.x;
  const int cf = t >> 5, sf = t & 31;
#pragma unroll
  for (int i = 0; i < 4; ++i) {
    const int c = c0 + cf + i * 8;
    tile[cf + i * 8][sf] = x[((size_t)b * 512 + c) * 1024 + s0 + sf];
  }
  __syncthreads();
  const int cl = t & 31, sl = t >> 5;
  const int cg = c0 + cl;
  const int j = cg >> 2;
  const float dv = expf((float)j * (-9.210340371976184f / 256.0f));
#pragma unroll
  for (int i = 0; i < 4; ++i) {
    const int s = s0 + sl + i * 8;
    const float pos = (cg & 2) ? (float)(s & 31) : (float)(s >> 5);
    const float arg = pos * dv;
    const float pe = (cg & 1) ? cosf(arg) : sinf(arg);
    const float v = tile[cl][sl + i * 8] + pe;
    const size_t r = (size_t)b * 1024 + s;
    Xp[r * 512 + cg] = f2bf(v);
    resid[r * 512 + cg] = v;
  }
}

// ---------------------------------------------------------------------------
// C[M,N] = A[M,K] @ Bt[N,K]^T, bf16 in, fp32 accum. 128x128 tile, BK=64.
template<int EPI>
__global__ __launch_bounds__(256) void gemm_bt(
    const u16* __restrict__ A, const u16* __restrict__ Bt, void* __restrict__ Cout,
    int M, int N, int K, float alpha,
    const float* __restrict__ bias, const float* __restrict__ resid) {
  __shared__ __align__(16) u16 As[128 * 64];
  __shared__ __align__(16) u16 Bs[128 * 64];
  const int t = threadIdx.x, lane = t & 63, wave = t >> 6;
  const int bn0 = blockIdx.x * 128, bm0 = blockIdx.y * 128;
  const int wr = wave >> 1, wc = wave & 1;
  const u16* Ag = A + (size_t)bm0 * K;
  const u16* Bg = Bt + (size_t)bn0 * K;
  f32x4 acc[4][4] = {};
  for (int kt = 0; kt < K; kt += 64) {
    __syncthreads();
    stage_rows<32>(Ag + kt, K, As, wave, lane);
    stage_rows<32>(Bg + kt, K, Bs, wave, lane);
    __syncthreads();
#pragma unroll
    for (int ks = 0; ks < 2; ++ks) {
      bf16x8 af[4], bfr[4];
#pragma unroll
      for (int m = 0; m < 4; ++m)
        af[m] = frag_read(As, wr * 64 + m * 16 + (lane & 15), ks * 4 + (lane >> 4));
#pragma unroll
      for (int n = 0; n < 4; ++n)
        bfr[n] = frag_read(Bs, wc * 64 + n * 16 + (lane & 15), ks * 4 + (lane >> 4));
#pragma unroll
      for (int m = 0; m < 4; ++m)
#pragma unroll
        for (int n = 0; n < 4; ++n)
          acc[m][n] = mfma16(af[m], bfr[n], acc[m][n]);
    }
  }
  const int cl = lane & 15, rg = (lane >> 4) * 4;
#pragma unroll
  for (int m = 0; m < 4; ++m)
#pragma unroll
    for (int n = 0; n < 4; ++n) {
      const int col = bn0 + wc * 64 + n * 16 + cl;
#pragma unroll
      for (int r = 0; r < 4; ++r) {
        const int row = bm0 + wr * 64 + m * 16 + rg + r;
        const float v = acc[m][n][r];
        if (EPI == 0) {
          ((u16*)Cout)[(size_t)row * N + col] = f2bf(v * alpha);
        } else {
          ((float*)Cout)[(size_t)row * N + col] =
              v + bias[col] + resid[(size_t)row * N + col];
        }
      }
    }
}

// ---------------------------------------------------------------------------
// Flash attention v2: swapped-operand 32x32x16 MFMA, in-register softmax,
// cvt_pk + permlane32_swap P-redistribution, double-buffered K/V staging.
// Grid: 512 1D blocks; wg -> b = wg&7 (XCD-resident K/V), h = (wg>>3)&7, qt = wg>>6.
// Block: 4 waves x 32 q rows = 128 q. KV tiles of 64.
// Q prescaled by (1/sqrt(dk))*log2(e) so softmax uses exp2.
__global__ __launch_bounds__(256, 2) void attn(
    const u16* __restrict__ Qb, const u16* __restrict__ Kb,
    const u16* __restrict__ Vt, u16* __restrict__ Ob) {
  __shared__ __align__(16) u16 Ks[2][64 * 64];
  __shared__ __align__(16) u16 Vs[2][64 * 64];
  const int t = threadIdx.x, lane = t & 63, wave = t >> 6;
  const int wg = blockIdx.x;
  const int b = wg & 7, h = (wg >> 3) & 7, qt = wg >> 6;
  const int ql = lane & 31, hl = lane >> 5;
  const int q0 = qt * 128 + wave * 32;               // q base for this wave
  // Q B-fragments straight from global: Bt[col=q][k=d], d = c*16 + hl*8 + j
  bf16x8 bq[4];
  {
    const u16* qrow = Qb + ((size_t)b * 1024 + q0 + ql) * 512 + h * 64 + hl * 8;
#pragma unroll
    for (int c = 0; c < 4; ++c) bq[c] = *(const bf16x8*)(qrow + c * 16);
  }
  f32x16 ot[2] = {};
  float m_run = -1e30f, l_run = 0.f;
  // prologue: stage tile 0 into buf 0
  stage_rows<16>(Kb + ((size_t)b * 1024 + 0) * 512 + h * 64, 512, Ks[0], wave, lane);
  stage_rows<16>(Vt + (size_t)(h * 64) * 8192 + (size_t)b * 1024 + 0, 8192, Vs[0], wave, lane);
  __syncthreads();
  int cur = 0;
  for (int kv = 0; kv < 16; ++kv) {
    // issue next-tile staging first: overlaps with this tile's compute
    if (kv < 15) {
      stage_rows<16>(Kb + ((size_t)b * 1024 + (kv + 1) * 64) * 512 + h * 64, 512,
                     Ks[cur ^ 1], wave, lane);
      stage_rows<16>(Vt + (size_t)(h * 64) * 8192 + (size_t)b * 1024 + (kv + 1) * 64, 8192,
                     Vs[cur ^ 1], wave, lane);
    }
    // S^T[k][q] = K[k][:] . Q[q][:]  (A = K rows, B = Q)
    f32x16 st[2] = {};
#pragma unroll
    for (int c = 0; c < 4; ++c) {
      bf16x8 a0 = frag_read(Ks[cur], ql, c * 2 + hl);
      bf16x8 a1 = frag_read(Ks[cur], 32 + ql, c * 2 + hl);
      st[0] = mfma32(a0, bq[c], st[0]);
      st[1] = mfma32(a1, bq[c], st[1]);
    }
    // ---- online softmax (lane owns one q; 32 of 64 k-values, partner lane has rest)
    float m0[8];
#pragma unroll
    for (int i = 0; i < 8; ++i)
      m0[i] = fmaxf(fmaxf(st[0][i], st[0][i + 8]), fmaxf(st[1][i], st[1][i + 8]));
#pragma unroll
    for (int i = 0; i < 4; ++i) m0[i] = fmaxf(m0[i], m0[i + 4]);
    float mx = fmaxf(fmaxf(m0[0], m0[1]), fmaxf(m0[2], m0[3]));
    mx = fmaxf(mx, __shfl_xor(mx, 32));
    const float mn = fmaxf(m_run, mx);
    const float sc = exp2f(m_run - mn);
    m_run = mn;
#pragma unroll
    for (int i = 0; i < 16; ++i) {
      st[0][i] = exp2f(st[0][i] - mn);
      st[1][i] = exp2f(st[1][i] - mn);
    }
    float s0[8];
#pragma unroll
    for (int i = 0; i < 8; ++i)
      s0[i] = (st[0][i] + st[0][i + 8]) + (st[1][i] + st[1][i + 8]);
#pragma unroll
    for (int i = 0; i < 4; ++i) s0[i] = s0[i] + s0[i + 4];
    float rs = (s0[0] + s0[1]) + (s0[2] + s0[3]);
    rs += __shfl_xor(rs, 32);
    l_run = l_run * sc + rs;
    ot[0] *= sc;
    ot[1] *= sc;
    // ---- pack P to bf16 pairs: W[kf][m] = pack(p[2m], p[2m+1])
    u32 W[2][8];
#pragma unroll
    for (int kf = 0; kf < 2; ++kf)
#pragma unroll
      for (int m = 0; m < 8; ++m)
        W[kf][m] = cvt_pk_bf16(st[kf][2 * m], st[kf][2 * m + 1]);
    // ---- redistribute to PV B-operand + accumulate O^T[d][q] += V^T[d][k] P^T[k][q]
#pragma unroll
    for (int c = 0; c < 4; ++c) {
      const int kf = c >> 1, i0 = (c & 1) * 4;
      u32 w0 = W[kf][i0 + 0], w2 = W[kf][i0 + 2];
      u32 w1 = W[kf][i0 + 1], w3 = W[kf][i0 + 3];
      perm32swap(w0, w2);  // w0 = word0 (src half0), w2 = word2 (src half1)
      perm32swap(w1, w3);  // w1 = word1,             w3 = word3
      u32x4 wv; wv.x = w0; wv.y = w1; wv.z = w2; wv.w = w3;
      bf16x8 bp = *(bf16x8*)&wv;
      bf16x8 v0 = frag_read(Vs[cur], ql, c * 2 + hl);
      bf16x8 v1 = frag_read(Vs[cur], 32 + ql, c * 2 + hl);
      ot[0] = mfma32(v0, bp, ot[0]);
      ot[1] = mfma32(v1, bp, ot[1]);
    }
    __syncthreads();   // drains vmcnt (next-tile stage) + lgkm, then barrier
    cur ^= 1;
  }
  // ---- write O: lane holds O^T[d][q] for q = q0+ql, d = df*32 + (reg&3)+8*(reg>>2)+4*hl
  const float inv = 1.f / l_run;
  u16* orow = Ob + ((size_t)b * 1024 + q0 + ql) * 512 + h * 64;
#pragma unroll
  for (int df = 0; df < 2; ++df)
#pragma unroll
    for (int r = 0; r < 16; ++r) {
      const int d = df * 32 + (r & 3) + 8 * (r >> 2) + 4 * hl;
      orow[d] = f2bf(ot[df][r] * inv);
    }
}

// ---------------------------------------------------------------------------
// LayerNorm over d=512 + transpose back to (B,C,H,W). grid (32 s-tiles, 8 b).
__global__ __launch_bounds__(256) void ln_out(
    const float* __restrict__ ypre, const float* __restrict__ gamma,
    const float* __restrict__ beta, float* __restrict__ out) {
  __shared__ float stats[32][2];
  __shared__ float tile[32][33];
  const int b = blockIdx.y, s0 = blockIdx.x * 32;
  const int t = threadIdx.x, lane = t & 63, wave = t >> 6;
  for (int i = 0; i < 8; ++i) {
    const int sl = wave * 8 + i;
    const float* row = ypre + ((size_t)b * 1024 + s0 + sl) * 512;
    float sum = 0.f, sq = 0.f;
#pragma unroll
    for (int k = 0; k < 8; ++k) {
      const float v = row[lane + 64 * k];
      sum += v; sq += v * v;
    }
#pragma unroll
    for (int off = 32; off >= 1; off >>= 1) {
      sum += __shfl_xor(sum, off);
      sq  += __shfl_xor(sq, off);
    }
    if (lane == 0) {
      const float mean = sum * (1.f / 512.f);
      const float var = sq * (1.f / 512.f) - mean * mean;
      stats[sl][0] = mean;
      stats[sl][1] = rsqrtf(var + 1e-5f);
    }
  }
  __syncthreads();
  const int cl = t & 31, sl8 = t >> 5;
  for (int cc = 0; cc < 16; ++cc) {
    const int c0 = cc * 32;
    if (cc) __syncthreads();
#pragma unroll
    for (int i = 0; i < 4; ++i) {
      const int s = sl8 + i * 8;
      const float v = ypre[((size_t)b * 1024 + s0 + s) * 512 + c0 + cl];
      tile[s][cl] = (v - stats[s][0]) * stats[s][1];
    }
    __syncthreads();
#pragma unroll
    for (int i = 0; i < 4; ++i) {
      const int c = c0 + sl8 + i * 8;
      out[((size_t)b * 512 + c) * 1024 + s0 + cl] = tile[cl][sl8 + i * 8] * gamma[c] + beta[c];
    }
  }
}

// ---------------------------------------------------------------------------
extern "C" void kernel_launch(void* const* d_in, const int* in_sizes, int n_in,
                              void* d_out, int out_size, void* d_ws, size_t ws_size,
                              hipStream_t stream) {
  const float* x     = (const float*)d_in[0];
  const float* Wq    = (const float*)d_in[1];
  const float* Wk    = (const float*)d_in[2];
  const float* Wv    = (const float*)d_in[3];
  const float* Wo    = (const float*)d_in[4];
  const float* bo    = (const float*)d_in[5];
  const float* gamma = (const float*)d_in[6];
  const float* beta  = (const float*)d_in[7];
  char* ws = (char*)d_ws;
  const size_t MB = 1048576;
  u16*   Xp    = (u16*)(ws);             //  8 MB bf16 (8192,512): x + PE
  u16*   Wb    = (u16*)(ws + 8 * MB);    //  2 MB bf16 weights [q][k][v][o]
  float* resid = (float*)(ws + 10 * MB); // 16 MB fp32 (8192,512)
  u16*   Qb    = (u16*)(ws + 26 * MB);   //  8 MB
  u16*   Kb    = (u16*)(ws + 34 * MB);   //  8 MB
  u16*   Vtb   = (u16*)(ws + 42 * MB);   //  8 MB bf16 V^T (512, 8192)
  u16*   Ob    = (u16*)(ws + 50 * MB);   //  8 MB attention out
  float* ypre  = (float*)(ws + 26 * MB); // 16 MB, reuses dead Qb/Kb region

  convert_w<<<dim3(256, 4), 256, 0, stream>>>(Wq, Wk, Wv, Wo, Wb);
  prep_x<<<dim3(32, 16, 8), 256, 0, stream>>>(x, Xp, resid);
  // Q = (Xp @ Wq^T) * (1/sqrt(dk)) * log2(e)   (softmax uses exp2)
  gemm_bt<0><<<dim3(4, 64), 256, 0, stream>>>(Xp, Wb,          (void*)Qb, 8192, 512, 512, 0.125f * 1.44269504088896f, nullptr, nullptr);
  gemm_bt<0><<<dim3(4, 64), 256, 0, stream>>>(Xp, Wb + 262144, (void*)Kb, 8192, 512, 512, 1.0f, nullptr, nullptr);
  // V^T = Wv @ Xp^T
  gemm_bt<0><<<dim3(64, 4), 256, 0, stream>>>(Wb + 2 * 262144, Xp, (void*)Vtb, 512, 8192, 512, 1.0f, nullptr, nullptr);
  attn<<<512, 256, 0, stream>>>(Qb, Kb, Vtb, Ob);
  // ypre = Ob @ Wo^T + bo + resid
  gemm_bt<1><<<dim3(4, 64), 256, 0, stream>>>(Ob, Wb + 3 * 262144, (void*)ypre, 8192, 512, 512, 1.0f, bo, resid);
  ln_out<<<dim3(32, 8), 256, 0, stream>>>(ypre, gamma, beta, (float*)d_out);
}

// Round 3
// 106.101 us; speedup vs baseline: 1.4304x; 1.2157x over previous
//
#include <hip/hip_runtime.h>
#include <hip/hip_bf16.h>
#include <math.h>

#define DEV static __device__ __forceinline__

typedef unsigned short u16;
typedef unsigned int u32;
typedef __attribute__((ext_vector_type(4))) float f32x4;
typedef __attribute__((ext_vector_type(16))) float f32x16;
typedef __attribute__((ext_vector_type(8))) __bf16 bf16x8;
typedef __attribute__((ext_vector_type(4))) u16 u16x4;
typedef __attribute__((ext_vector_type(4))) u32 u32x4;

// float -> bf16 bits, round-to-nearest-even
DEV u16 f2bf(float f) {
  unsigned u = __float_as_uint(f);
  u += 0x7fffu + ((u >> 16) & 1u);
  return (u16)(u >> 16);
}

DEV u32 cvt_pk_bf16(float lo, float hi) {
  u32 r;
  asm("v_cvt_pk_bf16_f32 %0, %1, %2" : "=v"(r) : "v"(lo), "v"(hi));
  return r;
}

// v_permlane32_swap_b32: a' = {a.lo, b.lo}, b' = {a.hi, b.hi}
DEV void perm32swap(u32& a, u32& b) {
  asm("v_permlane32_swap_b32 %0, %1" : "+v"(a), "+v"(b));
}

DEV void gl2lds16(const void* g, void* l) {
  __builtin_amdgcn_global_load_lds(
      (const __attribute__((address_space(1))) void*)g,
      (__attribute__((address_space(3))) void*)l, 16, 0, 0);
}

// Stage RPW rows (per wave) x 64 bf16 cols from global (row stride = gstride elems)
// into linear LDS [rows][64]. global_load_lds writes LDS linearly, so the XOR
// bank-swizzle is applied to the GLOBAL source slot (both-sides-or-neither).
// LDS[row][slot] <- global[row][slot ^ (row&7)].
template<int RPW>
DEV void stage_rows(const u16* __restrict__ g, int gstride, u16* lds, int wave, int lane) {
  const int r_in = lane >> 3, slot = lane & 7;
  const int base_row = wave * RPW;
#pragma unroll
  for (int i = 0; i < RPW / 8; ++i) {
    const int row = base_row + i * 8 + r_in;
    const int sslot = slot ^ (row & 7);
    gl2lds16(g + (size_t)row * gstride + sslot * 8,
             lds + (size_t)(base_row + i * 8) * 64);
  }
}

// Read an 8-bf16 slot (16B) from the swizzled [rows][64] tile.
DEV bf16x8 frag_read(const u16* lds, int row, int kslot) {
  const int slot = kslot ^ (row & 7);
  return *(const bf16x8*)(lds + row * 64 + slot * 8);
}

DEV f32x4 mfma16(bf16x8 a, bf16x8 b, f32x4 c) {
  return __builtin_amdgcn_mfma_f32_16x16x32_bf16(a, b, c, 0, 0, 0);
}
DEV f32x16 mfma32(bf16x8 a, bf16x8 b, f32x16 c) {
  return __builtin_amdgcn_mfma_f32_32x32x16_bf16(a, b, c, 0, 0, 0);
}

// ---------------------------------------------------------------------------
// Weights fp32 -> bf16. grid (256, 4), block 256. dst: [Wq][Wk][Wv][Wo].
__global__ __launch_bounds__(256) void convert_w(
    const float* __restrict__ w0, const float* __restrict__ w1,
    const float* __restrict__ w2, const float* __restrict__ w3,
    u16* __restrict__ dst) {
  const float* src = (blockIdx.y == 0) ? w0 : (blockIdx.y == 1) ? w1
                   : (blockIdx.y == 2) ? w2 : w3;
  const size_t base = (size_t)blockIdx.y * 262144;
  const int i = (blockIdx.x * 256 + threadIdx.x) * 4;
  f32x4 v = *(const f32x4*)(src + i);
  u16x4 o;
  o.x = f2bf(v.x); o.y = f2bf(v.y); o.z = f2bf(v.z); o.w = f2bf(v.w);
  *(u16x4*)(dst + base + i) = o;
}

// ---------------------------------------------------------------------------
// x (B,C,H,W) -> Xp bf16 (B*S, D) and resid fp32, adding 2D positional encoding.
__global__ __launch_bounds__(256) void prep_x(
    const float* __restrict__ x, u16* __restrict__ Xp, float* __restrict__ resid) {
  __shared__ float tile[32][33];
  const int b = blockIdx.z, c0 = blockIdx.y * 32, s0 = blockIdx.x * 32;
  const int t = threadIdx.x;
  const int cf = t >> 5, sf = t & 31;
#pragma unroll
  for (int i = 0; i < 4; ++i) {
    const int c = c0 + cf + i * 8;
    tile[cf + i * 8][sf] = x[((size_t)b * 512 + c) * 1024 + s0 + sf];
  }
  __syncthreads();
  const int cl = t & 31, sl = t >> 5;
  const int cg = c0 + cl;
  const int j = cg >> 2;
  const float dv = expf((float)j * (-9.210340371976184f / 256.0f));
#pragma unroll
  for (int i = 0; i < 4; ++i) {
    const int s = s0 + sl + i * 8;
    const float pos = (cg & 2) ? (float)(s & 31) : (float)(s >> 5);
    const float arg = pos * dv;
    const float pe = (cg & 1) ? cosf(arg) : sinf(arg);
    const float v = tile[cl][sl + i * 8] + pe;
    const size_t r = (size_t)b * 1024 + s;
    Xp[r * 512 + cg] = f2bf(v);
    resid[r * 512 + cg] = v;
  }
}

// ---------------------------------------------------------------------------
// Fused QKV GEMM: C[8192,1536] = Xp @ [Wq;Wk;Wv]^T, K=512, 128x128 tiles,
// grid (12, 64) = 768 blocks (3/CU). Epilogue routes by column region:
//   cols [0,512)    -> Qb, scaled by qscale (1/sqrt(dk) * log2 e)
//   cols [512,1024) -> Kb
//   cols [1024,1536)-> Vtb TRANSPOSED (Vtb[d][row]) via packed u16x4 stores
__global__ __launch_bounds__(256) void gemm_qkv(
    const u16* __restrict__ Xp, const u16* __restrict__ Wb,
    u16* __restrict__ Qb, u16* __restrict__ Kb, u16* __restrict__ Vtb,
    float qscale) {
  __shared__ __align__(16) u16 As[128 * 64];
  __shared__ __align__(16) u16 Bs[128 * 64];
  const int t = threadIdx.x, lane = t & 63, wave = t >> 6;
  const int bn0 = blockIdx.x * 128, bm0 = blockIdx.y * 128;
  const int wr = wave >> 1, wc = wave & 1;
  const u16* Ag = Xp + (size_t)bm0 * 512;
  const u16* Bg = Wb + (size_t)bn0 * 512;
  f32x4 acc[4][4] = {};
  for (int kt = 0; kt < 512; kt += 64) {
    __syncthreads();
    stage_rows<32>(Ag + kt, 512, As, wave, lane);
    stage_rows<32>(Bg + kt, 512, Bs, wave, lane);
    __syncthreads();
#pragma unroll
    for (int ks = 0; ks < 2; ++ks) {
      bf16x8 af[4], bfr[4];
#pragma unroll
      for (int m = 0; m < 4; ++m)
        af[m] = frag_read(As, wr * 64 + m * 16 + (lane & 15), ks * 4 + (lane >> 4));
#pragma unroll
      for (int n = 0; n < 4; ++n)
        bfr[n] = frag_read(Bs, wc * 64 + n * 16 + (lane & 15), ks * 4 + (lane >> 4));
#pragma unroll
      for (int m = 0; m < 4; ++m)
#pragma unroll
        for (int n = 0; n < 4; ++n)
          acc[m][n] = mfma16(af[m], bfr[n], acc[m][n]);
    }
  }
  const int cl = lane & 15, rg = (lane >> 4) * 4;
  const int colbase = bn0 + wc * 64;        // wave's 64-col range, one region
  const int region = colbase >> 9;          // 0=Q, 1=K, 2=V
  if (region == 2) {
#pragma unroll
    for (int m = 0; m < 4; ++m)
#pragma unroll
      for (int n = 0; n < 4; ++n) {
        const int dv = colbase + n * 16 + cl - 1024;
        const int row0 = bm0 + wr * 64 + m * 16 + rg;
        u16x4 pk;
#pragma unroll
        for (int r = 0; r < 4; ++r) pk[r] = f2bf(acc[m][n][r]);
        *(u16x4*)(Vtb + (size_t)dv * 8192 + row0) = pk;
      }
  } else {
    u16* dst = region ? Kb : Qb;
    const float al = region ? 1.0f : qscale;
    const int cb = colbase & 511;
#pragma unroll
    for (int m = 0; m < 4; ++m)
#pragma unroll
      for (int n = 0; n < 4; ++n) {
        const int col = cb + n * 16 + cl;
#pragma unroll
        for (int r = 0; r < 4; ++r) {
          const int row = bm0 + wr * 64 + m * 16 + rg + r;
          dst[(size_t)row * 512 + col] = f2bf(acc[m][n][r] * al);
        }
      }
  }
}

// ---------------------------------------------------------------------------
// Out-proj GEMM: ypre[8192,512] = Ob @ Wo^T + bo + resid, fp32 out.
// 128x64 tiles, grid (8, 64) = 512 blocks (2/CU). 4 waves 2x2, wave = 64x32.
__global__ __launch_bounds__(256) void gemm_out(
    const u16* __restrict__ A, const u16* __restrict__ Bt,
    float* __restrict__ ypre, const float* __restrict__ bias,
    const float* __restrict__ resid) {
  __shared__ __align__(16) u16 As[128 * 64];
  __shared__ __align__(16) u16 Bs[64 * 64];
  const int t = threadIdx.x, lane = t & 63, wave = t >> 6;
  const int bn0 = blockIdx.x * 64, bm0 = blockIdx.y * 128;
  const int wr = wave >> 1, wc = wave & 1;
  const u16* Ag = A + (size_t)bm0 * 512;
  const u16* Bg = Bt + (size_t)bn0 * 512;
  f32x4 acc[4][2] = {};
  for (int kt = 0; kt < 512; kt += 64) {
    __syncthreads();
    stage_rows<32>(Ag + kt, 512, As, wave, lane);
    stage_rows<16>(Bg + kt, 512, Bs, wave, lane);
    __syncthreads();
#pragma unroll
    for (int ks = 0; ks < 2; ++ks) {
      bf16x8 af[4], bfr[2];
#pragma unroll
      for (int m = 0; m < 4; ++m)
        af[m] = frag_read(As, wr * 64 + m * 16 + (lane & 15), ks * 4 + (lane >> 4));
#pragma unroll
      for (int n = 0; n < 2; ++n)
        bfr[n] = frag_read(Bs, wc * 32 + n * 16 + (lane & 15), ks * 4 + (lane >> 4));
#pragma unroll
      for (int m = 0; m < 4; ++m)
#pragma unroll
        for (int n = 0; n < 2; ++n)
          acc[m][n] = mfma16(af[m], bfr[n], acc[m][n]);
    }
  }
  const int cl = lane & 15, rg = (lane >> 4) * 4;
#pragma unroll
  for (int m = 0; m < 4; ++m)
#pragma unroll
    for (int n = 0; n < 2; ++n) {
      const int col = bn0 + wc * 32 + n * 16 + cl;
#pragma unroll
      for (int r = 0; r < 4; ++r) {
        const int row = bm0 + wr * 64 + m * 16 + rg + r;
        ypre[(size_t)row * 512 + col] =
            acc[m][n][r] + bias[col] + resid[(size_t)row * 512 + col];
      }
    }
}

// ---------------------------------------------------------------------------
// Flash attention v3: split-K across wave pairs + online-softmax merge.
// Grid 1024 blocks; wg -> b = wg&7 (XCD-resident K/V), h = (wg>>3)&7, qt = wg>>6.
// Block = 4 waves: qsub = wave&1 (32 q-rows each), half = wave>>1 (kv tiles
// half*8 .. half*8+7). Single-buffered K/V per half (32KB LDS) -> 4 blocks/CU.
// Swapped-operand 32x32x16 MFMA, in-register softmax (exp2, Q prescaled by
// log2e/sqrt(dk)), cvt_pk + permlane32_swap P-redistribution, defer-max (T13).
__global__ __launch_bounds__(256, 4) void attn(
    const u16* __restrict__ Qb, const u16* __restrict__ Kb,
    const u16* __restrict__ Vt, u16* __restrict__ Ob) {
  __shared__ __align__(16) u16 Ks[2][64 * 64];
  __shared__ __align__(16) u16 Vs[2][64 * 64];
  const int t = threadIdx.x, lane = t & 63, wave = t >> 6;
  const int wg = blockIdx.x;
  const int b = wg & 7, h = (wg >> 3) & 7, qt = wg >> 6;
  const int qsub = wave & 1, half = wave >> 1;
  const int ql = lane & 31, hl = lane >> 5;
  const int q0 = qt * 64 + qsub * 32;
  // Q B-fragments straight from global: B[col=q][k=d]
  bf16x8 bq[4];
  {
    const u16* qrow = Qb + ((size_t)b * 1024 + q0 + ql) * 512 + h * 64 + hl * 8;
#pragma unroll
    for (int c = 0; c < 4; ++c) bq[c] = *(const bf16x8*)(qrow + c * 16);
  }
  f32x16 ot[2] = {};
  float m_run = -1e30f, l_run = 0.f;
  // this wave's staging duty: wave&1 stages V[half], else K[half]
  u16* stg_dst = qsub ? Vs[half] : Ks[half];
  for (int i = 0; i < 8; ++i) {
    const int kb = half * 512 + i * 64;   // k-offset of this half's tile i
    {
      const int r_in = lane >> 3, slot = lane & 7;
      const u16* src; size_t gs;
      if (qsub) { src = Vt + (size_t)(h * 64) * 8192 + (size_t)b * 1024 + kb; gs = 8192; }
      else      { src = Kb + ((size_t)b * 1024 + kb) * 512 + h * 64;          gs = 512; }
#pragma unroll
      for (int j = 0; j < 8; ++j) {
        const int row = j * 8 + r_in;
        const int ss = slot ^ (row & 7);
        gl2lds16(src + (size_t)row * gs + ss * 8, stg_dst + j * 512);
      }
    }
    __syncthreads();
    // S^T[k][q] = K[k][:] . Q[q][:]
    f32x16 st[2] = {};
#pragma unroll
    for (int c = 0; c < 4; ++c) {
      bf16x8 a0 = frag_read(Ks[half], ql, c * 2 + hl);
      bf16x8 a1 = frag_read(Ks[half], 32 + ql, c * 2 + hl);
      st[0] = mfma32(a0, bq[c], st[0]);
      st[1] = mfma32(a1, bq[c], st[1]);
    }
    // ---- online softmax with defer-max
    float m0[8];
#pragma unroll
    for (int i2 = 0; i2 < 8; ++i2)
      m0[i2] = fmaxf(fmaxf(st[0][i2], st[0][i2 + 8]), fmaxf(st[1][i2], st[1][i2 + 8]));
#pragma unroll
    for (int i2 = 0; i2 < 4; ++i2) m0[i2] = fmaxf(m0[i2], m0[i2 + 4]);
    float mx = fmaxf(fmaxf(m0[0], m0[1]), fmaxf(m0[2], m0[3]));
    mx = fmaxf(mx, __shfl_xor(mx, 32));
    if (!__all(mx <= m_run + 8.f)) {
      const float mn = fmaxf(m_run, mx);
      const float sc = exp2f(m_run - mn);
      m_run = mn;
      l_run *= sc;
      ot[0] *= sc;
      ot[1] *= sc;
    }
#pragma unroll
    for (int i2 = 0; i2 < 16; ++i2) {
      st[0][i2] = exp2f(st[0][i2] - m_run);
      st[1][i2] = exp2f(st[1][i2] - m_run);
    }
    float s0[8];
#pragma unroll
    for (int i2 = 0; i2 < 8; ++i2)
      s0[i2] = (st[0][i2] + st[0][i2 + 8]) + (st[1][i2] + st[1][i2 + 8]);
#pragma unroll
    for (int i2 = 0; i2 < 4; ++i2) s0[i2] = s0[i2] + s0[i2 + 4];
    float rs = (s0[0] + s0[1]) + (s0[2] + s0[3]);
    rs += __shfl_xor(rs, 32);
    l_run += rs;
    // ---- pack P -> bf16, redistribute, accumulate O^T += V^T P^T
#pragma unroll
    for (int c = 0; c < 4; ++c) {
      const int kf = c >> 1, i0 = (c & 1) * 4;
      u32 w0 = cvt_pk_bf16(st[kf][2 * i0 + 0], st[kf][2 * i0 + 1]);
      u32 w1 = cvt_pk_bf16(st[kf][2 * i0 + 2], st[kf][2 * i0 + 3]);
      u32 w2 = cvt_pk_bf16(st[kf][2 * i0 + 4], st[kf][2 * i0 + 5]);
      u32 w3 = cvt_pk_bf16(st[kf][2 * i0 + 6], st[kf][2 * i0 + 7]);
      perm32swap(w0, w2);
      perm32swap(w1, w3);
      u32x4 wv; wv.x = w0; wv.y = w1; wv.z = w2; wv.w = w3;
      bf16x8 bp = *(bf16x8*)&wv;
      bf16x8 v0 = frag_read(Vs[half], ql, c * 2 + hl);
      bf16x8 v1 = frag_read(Vs[half], 32 + ql, c * 2 + hl);
      ot[0] = mfma32(v0, bp, ot[0]);
      ot[1] = mfma32(v1, bp, ot[1]);
    }
    __syncthreads();
  }
  // ---- merge the two kv-halves (flash-decoding style) through LDS
  float* Om = (float*)&Ks[0][0] + qsub * 2048;   // [64 d][32 q] per qsub
  float* Ml = (float*)&Vs[0][0];                 // m,l per qsub: [qsub*64 + {0,32}+ql]
  if (wave >= 2) {
#pragma unroll
    for (int df = 0; df < 2; ++df)
#pragma unroll
      for (int r = 0; r < 16; ++r) {
        const int dr = (r & 3) + 8 * (r >> 2) + 4 * hl;
        Om[(df * 32 + dr) * 32 + ql] = ot[df][r];
      }
    if (hl == 0) {
      Ml[qsub * 64 + ql] = m_run;
      Ml[qsub * 64 + 32 + ql] = l_run;
    }
    __syncthreads();
  } else {
    __syncthreads();
    const float m2 = Ml[qsub * 64 + ql];
    const float l2 = Ml[qsub * 64 + 32 + ql];
    const float m = fmaxf(m_run, m2);
    const float a = exp2f(m_run - m);
    const float bsc = exp2f(m2 - m);
    const float inv = 1.f / (l_run * a + l2 * bsc);
    u16* orow = Ob + ((size_t)b * 1024 + q0 + ql) * 512 + h * 64;
#pragma unroll
    for (int df = 0; df < 2; ++df)
#pragma unroll
      for (int r = 0; r < 16; ++r) {
        const int dr = (r & 3) + 8 * (r >> 2) + 4 * hl;
        const float v = ot[df][r] * a + Om[(df * 32 + dr) * 32 + ql] * bsc;
        orow[df * 32 + dr] = f2bf(v * inv);
      }
  }
}

// ---------------------------------------------------------------------------
// Single-pass LayerNorm over d=512 + transpose to (B,C,H,W).
// grid (64 s-tiles of 16, 8 b), block 256. LDS tile stride 513 (conflict-free
// on both row-major stats reads and column-major transpose reads).
__global__ __launch_bounds__(256) void ln_out(
    const float* __restrict__ ypre, const float* __restrict__ gamma,
    const float* __restrict__ beta, float* __restrict__ out) {
  __shared__ float tile[16 * 513];
  __shared__ float stats[16][2];
  const int b = blockIdx.y, s0 = blockIdx.x * 16;
  const int t = threadIdx.x, lane = t & 63, wave = t >> 6;
  const float* src = ypre + ((size_t)b * 1024 + s0) * 512;
#pragma unroll
  for (int i = 0; i < 8; ++i) {
    const int flat = (i * 256 + t) * 4;
    const int row = flat >> 9, col = flat & 511;
    const f32x4 v = *(const f32x4*)(src + flat);
    float* d = tile + row * 513 + col;
    d[0] = v.x; d[1] = v.y; d[2] = v.z; d[3] = v.w;
  }
  __syncthreads();
#pragma unroll
  for (int i = 0; i < 4; ++i) {
    const int r = wave * 4 + i;
    float sum = 0.f, sq = 0.f;
#pragma unroll
    for (int k = 0; k < 8; ++k) {
      const float v = tile[r * 513 + lane + 64 * k];
      sum += v; sq += v * v;
    }
#pragma unroll
    for (int off = 32; off >= 1; off >>= 1) {
      sum += __shfl_xor(sum, off);
      sq  += __shfl_xor(sq, off);
    }
    if (lane == 0) {
      const float mean = sum * (1.f / 512.f);
      const float var = sq * (1.f / 512.f) - mean * mean;
      stats[r][0] = mean;
      stats[r][1] = rsqrtf(var + 1e-5f);
    }
  }
  __syncthreads();
  const int sl = t & 15, cg = t >> 4;
  float* outb = out + (size_t)b * 512 * 1024 + s0;
  const float mean = stats[sl][0], rstd = stats[sl][1];
#pragma unroll 4
  for (int i = 0; i < 32; ++i) {
    const int c = i * 16 + cg;
    const float v = (tile[sl * 513 + c] - mean) * rstd;
    outb[(size_t)c * 1024 + sl] = v * gamma[c] + beta[c];
  }
}

// ---------------------------------------------------------------------------
extern "C" void kernel_launch(void* const* d_in, const int* in_sizes, int n_in,
                              void* d_out, int out_size, void* d_ws, size_t ws_size,
                              hipStream_t stream) {
  const float* x     = (const float*)d_in[0];
  const float* Wq    = (const float*)d_in[1];
  const float* Wk    = (const float*)d_in[2];
  const float* Wv    = (const float*)d_in[3];
  const float* Wo    = (const float*)d_in[4];
  const float* bo    = (const float*)d_in[5];
  const float* gamma = (const float*)d_in[6];
  const float* beta  = (const float*)d_in[7];
  char* ws = (char*)d_ws;
  const size_t MB = 1048576;
  u16*   Xp    = (u16*)(ws);             //  8 MB bf16 (8192,512): x + PE
  u16*   Wb    = (u16*)(ws + 8 * MB);    //  2 MB bf16 weights [q][k][v][o]
  float* resid = (float*)(ws + 10 * MB); // 16 MB fp32 (8192,512)
  u16*   Qb    = (u16*)(ws + 26 * MB);   //  8 MB
  u16*   Kb    = (u16*)(ws + 34 * MB);   //  8 MB
  u16*   Vtb   = (u16*)(ws + 42 * MB);   //  8 MB bf16 V^T (512, 8192)
  u16*   Ob    = (u16*)(ws + 50 * MB);   //  8 MB attention out
  float* ypre  = (float*)(ws + 26 * MB); // 16 MB, reuses dead Qb/Kb region

  convert_w<<<dim3(256, 4), 256, 0, stream>>>(Wq, Wk, Wv, Wo, Wb);
  prep_x<<<dim3(32, 16, 8), 256, 0, stream>>>(x, Xp, resid);
  // fused QKV: Q scaled by (1/sqrt(dk))*log2(e); V written transposed
  gemm_qkv<<<dim3(12, 64), 256, 0, stream>>>(Xp, Wb, Qb, Kb, Vtb,
                                             0.125f * 1.44269504088896f);
  attn<<<1024, 256, 0, stream>>>(Qb, Kb, Vtb, Ob);
  gemm_out<<<dim3(8, 64), 256, 0, stream>>>(Ob, Wb + 3 * 262144, ypre, bo, resid);
  ln_out<<<dim3(64, 8), 256, 0, stream>>>(ypre, gamma, beta, (float*)d_out);
}

// Round 4
// 106.010 us; speedup vs baseline: 1.4317x; 1.0009x over previous
//
#include <hip/hip_runtime.h>
#include <hip/hip_bf16.h>
#include <math.h>

#define DEV static __device__ __forceinline__

typedef unsigned short u16;
typedef unsigned int u32;
typedef __attribute__((ext_vector_type(4))) float f32x4;
typedef __attribute__((ext_vector_type(16))) float f32x16;
typedef __attribute__((ext_vector_type(8))) __bf16 bf16x8;
typedef __attribute__((ext_vector_type(4))) u16 u16x4;
typedef __attribute__((ext_vector_type(4))) u32 u32x4;

// float -> bf16 bits, round-to-nearest-even
DEV u16 f2bf(float f) {
  unsigned u = __float_as_uint(f);
  u += 0x7fffu + ((u >> 16) & 1u);
  return (u16)(u >> 16);
}
DEV float bf2f(u16 x) { return __uint_as_float((u32)x << 16); }

DEV u32 cvt_pk_bf16(float lo, float hi) {
  u32 r;
  asm("v_cvt_pk_bf16_f32 %0, %1, %2" : "=v"(r) : "v"(lo), "v"(hi));
  return r;
}

// v_permlane32_swap_b32: a' = {a.lo, b.lo}, b' = {a.hi, b.hi}
DEV void perm32swap(u32& a, u32& b) {
  asm("v_permlane32_swap_b32 %0, %1" : "+v"(a), "+v"(b));
}

DEV void gl2lds16(const void* g, void* l) {
  __builtin_amdgcn_global_load_lds(
      (const __attribute__((address_space(1))) void*)g,
      (__attribute__((address_space(3))) void*)l, 16, 0, 0);
}

// Stage RPW rows (per wave) x 64 bf16 cols from global (row stride = gstride elems)
// into linear LDS [rows][64]. global_load_lds writes LDS linearly, so the XOR
// bank-swizzle is applied to the GLOBAL source slot (both-sides-or-neither).
// LDS[row][slot] <- global[row][slot ^ (row&7)].
template<int RPW>
DEV void stage_rows(const u16* __restrict__ g, int gstride, u16* lds, int wave, int lane) {
  const int r_in = lane >> 3, slot = lane & 7;
  const int base_row = wave * RPW;
#pragma unroll
  for (int i = 0; i < RPW / 8; ++i) {
    const int row = base_row + i * 8 + r_in;
    const int sslot = slot ^ (row & 7);
    gl2lds16(g + (size_t)row * gstride + sslot * 8,
             lds + (size_t)(base_row + i * 8) * 64);
  }
}

// Read an 8-bf16 slot (16B) from the swizzled [rows][64] tile.
DEV bf16x8 frag_read(const u16* lds, int row, int kslot) {
  const int slot = kslot ^ (row & 7);
  return *(const bf16x8*)(lds + row * 64 + slot * 8);
}

DEV f32x4 mfma16(bf16x8 a, bf16x8 b, f32x4 c) {
  return __builtin_amdgcn_mfma_f32_16x16x32_bf16(a, b, c, 0, 0, 0);
}
DEV f32x16 mfma32(bf16x8 a, bf16x8 b, f32x16 c) {
  return __builtin_amdgcn_mfma_f32_32x32x16_bf16(a, b, c, 0, 0, 0);
}

// ---------------------------------------------------------------------------
// Weights fp32 -> bf16. grid (256, 4), block 256. dst: [Wq][Wk][Wv][Wo].
__global__ __launch_bounds__(256) void convert_w(
    const float* __restrict__ w0, const float* __restrict__ w1,
    const float* __restrict__ w2, const float* __restrict__ w3,
    u16* __restrict__ dst) {
  const float* src = (blockIdx.y == 0) ? w0 : (blockIdx.y == 1) ? w1
                   : (blockIdx.y == 2) ? w2 : w3;
  const size_t base = (size_t)blockIdx.y * 262144;
  const int i = (blockIdx.x * 256 + threadIdx.x) * 4;
  f32x4 v = *(const f32x4*)(src + i);
  u16x4 o;
  o.x = f2bf(v.x); o.y = f2bf(v.y); o.z = f2bf(v.z); o.w = f2bf(v.w);
  *(u16x4*)(dst + base + i) = o;
}

// ---------------------------------------------------------------------------
// x (B,C,H,W) -> Xp bf16 (B*S, D), adding 2D positional encoding.
// Xp doubles as the residual (read back as bf16 in gemm_out).
__global__ __launch_bounds__(256) void prep_x(
    const float* __restrict__ x, u16* __restrict__ Xp) {
  __shared__ float tile[32][33];
  const int b = blockIdx.z, c0 = blockIdx.y * 32, s0 = blockIdx.x * 32;
  const int t = threadIdx.x;
  const int cf = t >> 5, sf = t & 31;
#pragma unroll
  for (int i = 0; i < 4; ++i) {
    const int c = c0 + cf + i * 8;
    tile[cf + i * 8][sf] = x[((size_t)b * 512 + c) * 1024 + s0 + sf];
  }
  __syncthreads();
  const int cl = t & 31, sl = t >> 5;
  const int cg = c0 + cl;
  const int j = cg >> 2;
  const float dv = expf((float)j * (-9.210340371976184f / 256.0f));
#pragma unroll
  for (int i = 0; i < 4; ++i) {
    const int s = s0 + sl + i * 8;
    const float pos = (cg & 2) ? (float)(s & 31) : (float)(s >> 5);
    const float arg = pos * dv;
    const float pe = (cg & 1) ? cosf(arg) : sinf(arg);
    const float v = tile[cl][sl + i * 8] + pe;
    Xp[((size_t)b * 1024 + s) * 512 + cg] = f2bf(v);
  }
}

// ---------------------------------------------------------------------------
// Fused QKV GEMM: C[8192,1536] = Xp @ [Wq;Wk;Wv]^T, K=512, 128x128 tiles,
// grid (12, 64) = 768 blocks (3/CU). Epilogue routes by column region:
//   cols [0,512)    -> Qb, scaled by qscale (1/sqrt(dk) * log2 e)
//   cols [512,1024) -> Kb
//   cols [1024,1536)-> Vtb TRANSPOSED (Vtb[d][row]) via LDS transpose +
//                      coalesced u16x4 stores (256B runs per half-wave)
__global__ __launch_bounds__(256) void gemm_qkv(
    const u16* __restrict__ Xp, const u16* __restrict__ Wb,
    u16* __restrict__ Qb, u16* __restrict__ Kb, u16* __restrict__ Vtb,
    float qscale) {
  __shared__ __align__(16) u16 smem[128 * 132];   // 33,792 B; staging uses 32 KB
  u16* As = smem;
  u16* Bs = smem + 128 * 64;
  const int t = threadIdx.x, lane = t & 63, wave = t >> 6;
  const int bn0 = blockIdx.x * 128, bm0 = blockIdx.y * 128;
  const int wr = wave >> 1, wc = wave & 1;
  const u16* Ag = Xp + (size_t)bm0 * 512;
  const u16* Bg = Wb + (size_t)bn0 * 512;
  f32x4 acc[4][4] = {};
  for (int kt = 0; kt < 512; kt += 64) {
    __syncthreads();
    stage_rows<32>(Ag + kt, 512, As, wave, lane);
    stage_rows<32>(Bg + kt, 512, Bs, wave, lane);
    __syncthreads();
#pragma unroll
    for (int ks = 0; ks < 2; ++ks) {
      bf16x8 af[4], bfr[4];
#pragma unroll
      for (int m = 0; m < 4; ++m)
        af[m] = frag_read(As, wr * 64 + m * 16 + (lane & 15), ks * 4 + (lane >> 4));
#pragma unroll
      for (int n = 0; n < 4; ++n)
        bfr[n] = frag_read(Bs, wc * 64 + n * 16 + (lane & 15), ks * 4 + (lane >> 4));
#pragma unroll
      for (int m = 0; m < 4; ++m)
#pragma unroll
        for (int n = 0; n < 4; ++n)
          acc[m][n] = mfma16(af[m], bfr[n], acc[m][n]);
    }
  }
  const int cl = lane & 15, rg = (lane >> 4) * 4;
  if (bn0 >= 1024) {
    // ---- V region: transpose through LDS, then coalesced stores
    __syncthreads();   // staging reads done before overwrite
#pragma unroll
    for (int m = 0; m < 4; ++m)
#pragma unroll
      for (int n = 0; n < 4; ++n) {
        const int dvL = wc * 64 + n * 16 + cl;
        const int rowL0 = wr * 64 + m * 16 + rg;
        u16x4 pk;
#pragma unroll
        for (int r = 0; r < 4; ++r) pk[r] = f2bf(acc[m][n][r]);
        *(u16x4*)(smem + dvL * 132 + rowL0) = pk;
      }
    __syncthreads();
    const int dvg0 = bn0 - 1024;
#pragma unroll
    for (int i = 0; i < 16; ++i) {
      const int idx = i * 256 + t;          // 4096 u16x4 total
      const int dv = idx >> 5, ch = (idx & 31) * 4;
      const u16x4 v = *(const u16x4*)(smem + dv * 132 + ch);
      *(u16x4*)(Vtb + (size_t)(dvg0 + dv) * 8192 + bm0 + ch) = v;
    }
  } else {
    u16* dst = (bn0 >= 512) ? Kb : Qb;
    const float al = (bn0 >= 512) ? 1.0f : qscale;
    const int cb = (bn0 & 511) + wc * 64;
#pragma unroll
    for (int m = 0; m < 4; ++m)
#pragma unroll
      for (int n = 0; n < 4; ++n) {
        const int col = cb + n * 16 + cl;
#pragma unroll
        for (int r = 0; r < 4; ++r) {
          const int row = bm0 + wr * 64 + m * 16 + rg + r;
          dst[(size_t)row * 512 + col] = f2bf(acc[m][n][r] * al);
        }
      }
  }
}

// ---------------------------------------------------------------------------
// Out-proj GEMM: ypre[8192,512] = Ob @ Wo^T + bo + resid(bf16 Xp), fp32 out.
// 128x64 tiles, grid (8, 64) = 512 blocks (2/CU).
__global__ __launch_bounds__(256) void gemm_out(
    const u16* __restrict__ A, const u16* __restrict__ Bt,
    float* __restrict__ ypre, const float* __restrict__ bias,
    const u16* __restrict__ residb) {
  __shared__ __align__(16) u16 As[128 * 64];
  __shared__ __align__(16) u16 Bs[64 * 64];
  const int t = threadIdx.x, lane = t & 63, wave = t >> 6;
  const int bn0 = blockIdx.x * 64, bm0 = blockIdx.y * 128;
  const int wr = wave >> 1, wc = wave & 1;
  const u16* Ag = A + (size_t)bm0 * 512;
  const u16* Bg = Bt + (size_t)bn0 * 512;
  f32x4 acc[4][2] = {};
  for (int kt = 0; kt < 512; kt += 64) {
    __syncthreads();
    stage_rows<32>(Ag + kt, 512, As, wave, lane);
    stage_rows<16>(Bg + kt, 512, Bs, wave, lane);
    __syncthreads();
#pragma unroll
    for (int ks = 0; ks < 2; ++ks) {
      bf16x8 af[4], bfr[2];
#pragma unroll
      for (int m = 0; m < 4; ++m)
        af[m] = frag_read(As, wr * 64 + m * 16 + (lane & 15), ks * 4 + (lane >> 4));
#pragma unroll
      for (int n = 0; n < 2; ++n)
        bfr[n] = frag_read(Bs, wc * 32 + n * 16 + (lane & 15), ks * 4 + (lane >> 4));
#pragma unroll
      for (int m = 0; m < 4; ++m)
#pragma unroll
        for (int n = 0; n < 2; ++n)
          acc[m][n] = mfma16(af[m], bfr[n], acc[m][n]);
    }
  }
  const int cl = lane & 15, rg = (lane >> 4) * 4;
#pragma unroll
  for (int m = 0; m < 4; ++m)
#pragma unroll
    for (int n = 0; n < 2; ++n) {
      const int col = bn0 + wc * 32 + n * 16 + cl;
#pragma unroll
      for (int r = 0; r < 4; ++r) {
        const int row = bm0 + wr * 64 + m * 16 + rg + r;
        ypre[(size_t)row * 512 + col] =
            acc[m][n][r] + bias[col] + bf2f(residb[(size_t)row * 512 + col]);
      }
    }
}

// ---------------------------------------------------------------------------
// Flash attention v4: swapped-operand 32x32x16 MFMA, in-register softmax
// (exp2, Q prescaled), cvt_pk + permlane32_swap, defer-max, and a TRUE
// double-buffered pipeline: raw s_barrier + counted s_waitcnt vmcnt(4) so
// next-tile global_load_lds stays in flight across the barrier (T3+T4).
// Grid 512 1D; wg -> b = wg&7 (XCD-resident K/V), h = (wg>>3)&7, qt = wg>>6.
// Block: 4 waves x 32 q rows = 128 q. KV tiles of 64.
__global__ __launch_bounds__(256) void attn(
    const u16* __restrict__ Qb, const u16* __restrict__ Kb,
    const u16* __restrict__ Vt, u16* __restrict__ Ob) {
  __shared__ __align__(16) u16 Ks[2][64 * 64];
  __shared__ __align__(16) u16 Vs[2][64 * 64];
  const int t = threadIdx.x, lane = t & 63, wave = t >> 6;
  const int wg = blockIdx.x;
  const int b = wg & 7, h = (wg >> 3) & 7, qt = wg >> 6;
  const int ql = lane & 31, hl = lane >> 5;
  const int q0 = qt * 128 + wave * 32;
  // Q B-fragments straight from global: B[col=q][k=d]
  bf16x8 bq[4];
  {
    const u16* qrow = Qb + ((size_t)b * 1024 + q0 + ql) * 512 + h * 64 + hl * 8;
#pragma unroll
    for (int c = 0; c < 4; ++c) bq[c] = *(const bf16x8*)(qrow + c * 16);
  }
  f32x16 ot[2] = {};
  float m_run = -1e30f, l_run = 0.f;
  const u16* Kg = Kb + (size_t)b * 1024 * 512 + h * 64;
  const u16* Vg = Vt + (size_t)(h * 64) * 8192 + (size_t)b * 1024;
  // prologue: stage tile 0 into buf 0 (4 gl2lds per wave: 2 K + 2 V)
  stage_rows<16>(Kg, 512, Ks[0], wave, lane);
  stage_rows<16>(Vg, 8192, Vs[0], wave, lane);
  int cur = 0;
  for (int kv = 0; kv < 16; ++kv) {
    if (kv < 15) {
      stage_rows<16>(Kg + (size_t)(kv + 1) * 64 * 512, 512, Ks[cur ^ 1], wave, lane);
      stage_rows<16>(Vg + (kv + 1) * 64, 8192, Vs[cur ^ 1], wave, lane);
      __builtin_amdgcn_sched_barrier(0);
      asm volatile("s_waitcnt vmcnt(4)" ::: "memory");   // tile kv landed; kv+1 in flight
    } else {
      asm volatile("s_waitcnt vmcnt(0)" ::: "memory");
    }
    __builtin_amdgcn_s_barrier();
    __builtin_amdgcn_sched_barrier(0);
    // S^T[k][q] = K[k][:] . Q[q][:]
    f32x16 st[2] = {};
#pragma unroll
    for (int c = 0; c < 4; ++c) {
      bf16x8 a0 = frag_read(Ks[cur], ql, c * 2 + hl);
      bf16x8 a1 = frag_read(Ks[cur], 32 + ql, c * 2 + hl);
      st[0] = mfma32(a0, bq[c], st[0]);
      st[1] = mfma32(a1, bq[c], st[1]);
    }
    // ---- online softmax with defer-max
    float m0[8];
#pragma unroll
    for (int i2 = 0; i2 < 8; ++i2)
      m0[i2] = fmaxf(fmaxf(st[0][i2], st[0][i2 + 8]), fmaxf(st[1][i2], st[1][i2 + 8]));
#pragma unroll
    for (int i2 = 0; i2 < 4; ++i2) m0[i2] = fmaxf(m0[i2], m0[i2 + 4]);
    float mx = fmaxf(fmaxf(m0[0], m0[1]), fmaxf(m0[2], m0[3]));
    mx = fmaxf(mx, __shfl_xor(mx, 32));
    if (!__all(mx <= m_run + 8.f)) {
      const float mn = fmaxf(m_run, mx);
      const float sc = exp2f(m_run - mn);
      m_run = mn;
      l_run *= sc;
      ot[0] *= sc;
      ot[1] *= sc;
    }
#pragma unroll
    for (int i2 = 0; i2 < 16; ++i2) {
      st[0][i2] = exp2f(st[0][i2] - m_run);
      st[1][i2] = exp2f(st[1][i2] - m_run);
    }
    float s0[8];
#pragma unroll
    for (int i2 = 0; i2 < 8; ++i2)
      s0[i2] = (st[0][i2] + st[0][i2 + 8]) + (st[1][i2] + st[1][i2 + 8]);
#pragma unroll
    for (int i2 = 0; i2 < 4; ++i2) s0[i2] = s0[i2] + s0[i2 + 4];
    float rs = (s0[0] + s0[1]) + (s0[2] + s0[3]);
    rs += __shfl_xor(rs, 32);
    l_run += rs;
    // ---- pack P -> bf16, redistribute, accumulate O^T += V^T P^T
#pragma unroll
    for (int c = 0; c < 4; ++c) {
      const int kf = c >> 1, i0 = (c & 1) * 4;
      u32 w0 = cvt_pk_bf16(st[kf][2 * i0 + 0], st[kf][2 * i0 + 1]);
      u32 w1 = cvt_pk_bf16(st[kf][2 * i0 + 2], st[kf][2 * i0 + 3]);
      u32 w2 = cvt_pk_bf16(st[kf][2 * i0 + 4], st[kf][2 * i0 + 5]);
      u32 w3 = cvt_pk_bf16(st[kf][2 * i0 + 6], st[kf][2 * i0 + 7]);
      perm32swap(w0, w2);
      perm32swap(w1, w3);
      u32x4 wv; wv.x = w0; wv.y = w1; wv.z = w2; wv.w = w3;
      bf16x8 bp = *(bf16x8*)&wv;
      bf16x8 v0 = frag_read(Vs[cur], ql, c * 2 + hl);
      bf16x8 v1 = frag_read(Vs[cur], 32 + ql, c * 2 + hl);
      ot[0] = mfma32(v0, bp, ot[0]);
      ot[1] = mfma32(v1, bp, ot[1]);
    }
    __builtin_amdgcn_sched_barrier(0);
    __builtin_amdgcn_s_barrier();    // all waves done reading buf; safe to overwrite
    __builtin_amdgcn_sched_barrier(0);
    cur ^= 1;
  }
  // ---- write O: lane holds O^T[d][q] for q = q0+ql, d = df*32+(r&3)+8*(r>>2)+4*hl
  const float inv = 1.f / l_run;
  u16* orow = Ob + ((size_t)b * 1024 + q0 + ql) * 512 + h * 64;
#pragma unroll
  for (int df = 0; df < 2; ++df)
#pragma unroll
    for (int r = 0; r < 16; ++r) {
      const int d = df * 32 + (r & 3) + 8 * (r >> 2) + 4 * hl;
      orow[d] = f2bf(ot[df][r] * inv);
    }
}

// ---------------------------------------------------------------------------
// Single-pass LayerNorm over d=512 + transpose to (B,C,H,W).
// grid (64 s-tiles of 16, 8 b), block 256.
__global__ __launch_bounds__(256) void ln_out(
    const float* __restrict__ ypre, const float* __restrict__ gamma,
    const float* __restrict__ beta, float* __restrict__ out) {
  __shared__ float tile[16 * 513];
  __shared__ float stats[16][2];
  const int b = blockIdx.y, s0 = blockIdx.x * 16;
  const int t = threadIdx.x, lane = t & 63, wave = t >> 6;
  const float* src = ypre + ((size_t)b * 1024 + s0) * 512;
#pragma unroll
  for (int i = 0; i < 8; ++i) {
    const int flat = (i * 256 + t) * 4;
    const int row = flat >> 9, col = flat & 511;
    const f32x4 v = *(const f32x4*)(src + flat);
    float* d = tile + row * 513 + col;
    d[0] = v.x; d[1] = v.y; d[2] = v.z; d[3] = v.w;
  }
  __syncthreads();
#pragma unroll
  for (int i = 0; i < 4; ++i) {
    const int r = wave * 4 + i;
    float sum = 0.f, sq = 0.f;
#pragma unroll
    for (int k = 0; k < 8; ++k) {
      const float v = tile[r * 513 + lane + 64 * k];
      sum += v; sq += v * v;
    }
#pragma unroll
    for (int off = 32; off >= 1; off >>= 1) {
      sum += __shfl_xor(sum, off);
      sq  += __shfl_xor(sq, off);
    }
    if (lane == 0) {
      const float mean = sum * (1.f / 512.f);
      const float var = sq * (1.f / 512.f) - mean * mean;
      stats[r][0] = mean;
      stats[r][1] = rsqrtf(var + 1e-5f);
    }
  }
  __syncthreads();
  const int sl = t & 15, cg = t >> 4;
  float* outb = out + (size_t)b * 512 * 1024 + s0;
  const float mean = stats[sl][0], rstd = stats[sl][1];
#pragma unroll 4
  for (int i = 0; i < 32; ++i) {
    const int c = i * 16 + cg;
    const float v = (tile[sl * 513 + c] - mean) * rstd;
    outb[(size_t)c * 1024 + sl] = v * gamma[c] + beta[c];
  }
}

// ---------------------------------------------------------------------------
extern "C" void kernel_launch(void* const* d_in, const int* in_sizes, int n_in,
                              void* d_out, int out_size, void* d_ws, size_t ws_size,
                              hipStream_t stream) {
  const float* x     = (const float*)d_in[0];
  const float* Wq    = (const float*)d_in[1];
  const float* Wk    = (const float*)d_in[2];
  const float* Wv    = (const float*)d_in[3];
  const float* Wo    = (const float*)d_in[4];
  const float* bo    = (const float*)d_in[5];
  const float* gamma = (const float*)d_in[6];
  const float* beta  = (const float*)d_in[7];
  char* ws = (char*)d_ws;
  const size_t MB = 1048576;
  u16*   Xp    = (u16*)(ws);             //  8 MB bf16 (8192,512): x + PE (also residual)
  u16*   Wb    = (u16*)(ws + 8 * MB);    //  2 MB bf16 weights [q][k][v][o]
  u16*   Qb    = (u16*)(ws + 10 * MB);   //  8 MB
  u16*   Kb    = (u16*)(ws + 18 * MB);   //  8 MB
  u16*   Vtb   = (u16*)(ws + 26 * MB);   //  8 MB bf16 V^T (512, 8192)
  u16*   Ob    = (u16*)(ws + 34 * MB);   //  8 MB attention out
  float* ypre  = (float*)(ws + 42 * MB); // 16 MB fp32

  convert_w<<<dim3(256, 4), 256, 0, stream>>>(Wq, Wk, Wv, Wo, Wb);
  prep_x<<<dim3(32, 16, 8), 256, 0, stream>>>(x, Xp);
  // fused QKV: Q scaled by (1/sqrt(dk))*log2(e); V written transposed
  gemm_qkv<<<dim3(12, 64), 256, 0, stream>>>(Xp, Wb, Qb, Kb, Vtb,
                                             0.125f * 1.44269504088896f);
  attn<<<512, 256, 0, stream>>>(Qb, Kb, Vtb, Ob);
  gemm_out<<<dim3(8, 64), 256, 0, stream>>>(Ob, Wb + 3 * 262144, ypre, bo, Xp);
  ln_out<<<dim3(64, 8), 256, 0, stream>>>(ypre, gamma, beta, (float*)d_out);
}

// Round 5
// 95.377 us; speedup vs baseline: 1.5913x; 1.1115x over previous
//
#include <hip/hip_runtime.h>
#include <hip/hip_bf16.h>
#include <math.h>

#define DEV static __device__ __forceinline__

typedef unsigned short u16;
typedef unsigned int u32;
typedef __attribute__((ext_vector_type(4))) float f32x4;
typedef __attribute__((ext_vector_type(16))) float f32x16;
typedef __attribute__((ext_vector_type(8))) __bf16 bf16x8;
typedef __attribute__((ext_vector_type(4))) u16 u16x4;
typedef __attribute__((ext_vector_type(4))) u32 u32x4;

// float -> bf16 bits, round-to-nearest-even
DEV u16 f2bf(float f) {
  unsigned u = __float_as_uint(f);
  u += 0x7fffu + ((u >> 16) & 1u);
  return (u16)(u >> 16);
}
DEV float bf2f(u16 x) { return __uint_as_float((u32)x << 16); }

// single-instruction v_exp_f32 (exp2f may lower to a guarded libm call)
DEV float fexp2(float x) { return __builtin_amdgcn_exp2f(x); }

DEV u32 cvt_pk_bf16(float lo, float hi) {
  u32 r;
  asm("v_cvt_pk_bf16_f32 %0, %1, %2" : "=v"(r) : "v"(lo), "v"(hi));
  return r;
}

// v_permlane32_swap_b32: a' = {a.lo, b.lo}, b' = {a.hi, b.hi}
DEV void perm32swap(u32& a, u32& b) {
  asm("v_permlane32_swap_b32 %0, %1" : "+v"(a), "+v"(b));
}

DEV void gl2lds16(const void* g, void* l) {
  __builtin_amdgcn_global_load_lds(
      (const __attribute__((address_space(1))) void*)g,
      (__attribute__((address_space(3))) void*)l, 16, 0, 0);
}

// Stage RPW rows (per wave) x 64 bf16 cols from global (row stride = gstride elems)
// into linear LDS [rows][64]. global_load_lds writes LDS linearly, so the XOR
// bank-swizzle is applied to the GLOBAL source slot (both-sides-or-neither).
// LDS[row][slot] <- global[row][slot ^ (row&7)].
template<int RPW>
DEV void stage_rows(const u16* __restrict__ g, int gstride, u16* lds, int wave, int lane) {
  const int r_in = lane >> 3, slot = lane & 7;
  const int base_row = wave * RPW;
#pragma unroll
  for (int i = 0; i < RPW / 8; ++i) {
    const int row = base_row + i * 8 + r_in;
    const int sslot = slot ^ (row & 7);
    gl2lds16(g + (size_t)row * gstride + sslot * 8,
             lds + (size_t)(base_row + i * 8) * 64);
  }
}

// Read an 8-bf16 slot (16B) from the swizzled [rows][64] tile.
DEV bf16x8 frag_read(const u16* lds, int row, int kslot) {
  const int slot = kslot ^ (row & 7);
  return *(const bf16x8*)(lds + row * 64 + slot * 8);
}

DEV f32x4 mfma16(bf16x8 a, bf16x8 b, f32x4 c) {
  return __builtin_amdgcn_mfma_f32_16x16x32_bf16(a, b, c, 0, 0, 0);
}
DEV f32x16 mfma32(bf16x8 a, bf16x8 b, f32x16 c) {
  return __builtin_amdgcn_mfma_f32_32x32x16_bf16(a, b, c, 0, 0, 0);
}

// ---------------------------------------------------------------------------
// Weights fp32 -> bf16. grid (256, 4), block 256. dst: [Wq][Wk][Wv][Wo].
__global__ __launch_bounds__(256) void convert_w(
    const float* __restrict__ w0, const float* __restrict__ w1,
    const float* __restrict__ w2, const float* __restrict__ w3,
    u16* __restrict__ dst) {
  const float* src = (blockIdx.y == 0) ? w0 : (blockIdx.y == 1) ? w1
                   : (blockIdx.y == 2) ? w2 : w3;
  const size_t base = (size_t)blockIdx.y * 262144;
  const int i = (blockIdx.x * 256 + threadIdx.x) * 4;
  f32x4 v = *(const f32x4*)(src + i);
  u16x4 o;
  o.x = f2bf(v.x); o.y = f2bf(v.y); o.z = f2bf(v.z); o.w = f2bf(v.w);
  *(u16x4*)(dst + base + i) = o;
}

// ---------------------------------------------------------------------------
// x (B,C,H,W) -> Xp bf16 (B*S, D), adding 2D positional encoding.
// Xp doubles as the residual (read back as bf16 in gemm_out).
__global__ __launch_bounds__(256) void prep_x(
    const float* __restrict__ x, u16* __restrict__ Xp) {
  __shared__ float tile[32][33];
  const int b = blockIdx.z, c0 = blockIdx.y * 32, s0 = blockIdx.x * 32;
  const int t = threadIdx.x;
  const int cf = t >> 5, sf = t & 31;
#pragma unroll
  for (int i = 0; i < 4; ++i) {
    const int c = c0 + cf + i * 8;
    tile[cf + i * 8][sf] = x[((size_t)b * 512 + c) * 1024 + s0 + sf];
  }
  __syncthreads();
  const int cl = t & 31, sl = t >> 5;
  const int cg = c0 + cl;
  const int j = cg >> 2;
  const float dv = expf((float)j * (-9.210340371976184f / 256.0f));
#pragma unroll
  for (int i = 0; i < 4; ++i) {
    const int s = s0 + sl + i * 8;
    const float pos = (cg & 2) ? (float)(s & 31) : (float)(s >> 5);
    const float arg = pos * dv;
    const float pe = (cg & 1) ? cosf(arg) : sinf(arg);
    const float v = tile[cl][sl + i * 8] + pe;
    Xp[((size_t)b * 1024 + s) * 512 + cg] = f2bf(v);
  }
}

// ---------------------------------------------------------------------------
// Fused QKV GEMM: C[8192,1536] = Xp @ [Wq;Wk;Wv]^T, K=512, 128x128 tiles,
// grid (12, 64) = 768 blocks (3/CU). Epilogue routes by column region:
//   cols [0,512)    -> Qb, scaled by qscale (1/sqrt(dk) * log2 e)
//   cols [512,1024) -> Kb
//   cols [1024,1536)-> Vtb TRANSPOSED (Vtb[d][row]) via LDS transpose +
//                      coalesced u16x4 stores
__global__ __launch_bounds__(256) void gemm_qkv(
    const u16* __restrict__ Xp, const u16* __restrict__ Wb,
    u16* __restrict__ Qb, u16* __restrict__ Kb, u16* __restrict__ Vtb,
    float qscale) {
  __shared__ __align__(16) u16 smem[128 * 132];   // 33,792 B; staging uses 32 KB
  u16* As = smem;
  u16* Bs = smem + 128 * 64;
  const int t = threadIdx.x, lane = t & 63, wave = t >> 6;
  const int bn0 = blockIdx.x * 128, bm0 = blockIdx.y * 128;
  const int wr = wave >> 1, wc = wave & 1;
  const u16* Ag = Xp + (size_t)bm0 * 512;
  const u16* Bg = Wb + (size_t)bn0 * 512;
  f32x4 acc[4][4] = {};
  for (int kt = 0; kt < 512; kt += 64) {
    __syncthreads();
    stage_rows<32>(Ag + kt, 512, As, wave, lane);
    stage_rows<32>(Bg + kt, 512, Bs, wave, lane);
    __syncthreads();
#pragma unroll
    for (int ks = 0; ks < 2; ++ks) {
      bf16x8 af[4], bfr[4];
#pragma unroll
      for (int m = 0; m < 4; ++m)
        af[m] = frag_read(As, wr * 64 + m * 16 + (lane & 15), ks * 4 + (lane >> 4));
#pragma unroll
      for (int n = 0; n < 4; ++n)
        bfr[n] = frag_read(Bs, wc * 64 + n * 16 + (lane & 15), ks * 4 + (lane >> 4));
#pragma unroll
      for (int m = 0; m < 4; ++m)
#pragma unroll
        for (int n = 0; n < 4; ++n)
          acc[m][n] = mfma16(af[m], bfr[n], acc[m][n]);
    }
  }
  const int cl = lane & 15, rg = (lane >> 4) * 4;
  if (bn0 >= 1024) {
    // ---- V region: transpose through LDS, then coalesced stores
    __syncthreads();   // staging reads done before overwrite
#pragma unroll
    for (int m = 0; m < 4; ++m)
#pragma unroll
      for (int n = 0; n < 4; ++n) {
        const int dvL = wc * 64 + n * 16 + cl;
        const int rowL0 = wr * 64 + m * 16 + rg;
        u16x4 pk;
#pragma unroll
        for (int r = 0; r < 4; ++r) pk[r] = f2bf(acc[m][n][r]);
        *(u16x4*)(smem + dvL * 132 + rowL0) = pk;
      }
    __syncthreads();
    const int dvg0 = bn0 - 1024;
#pragma unroll
    for (int i = 0; i < 16; ++i) {
      const int idx = i * 256 + t;          // 4096 u16x4 total
      const int dv = idx >> 5, ch = (idx & 31) * 4;
      const u16x4 v = *(const u16x4*)(smem + dv * 132 + ch);
      *(u16x4*)(Vtb + (size_t)(dvg0 + dv) * 8192 + bm0 + ch) = v;
    }
  } else {
    u16* dst = (bn0 >= 512) ? Kb : Qb;
    const float al = (bn0 >= 512) ? 1.0f : qscale;
    const int cb = (bn0 & 511) + wc * 64;
#pragma unroll
    for (int m = 0; m < 4; ++m)
#pragma unroll
      for (int n = 0; n < 4; ++n) {
        const int col = cb + n * 16 + cl;
#pragma unroll
        for (int r = 0; r < 4; ++r) {
          const int row = bm0 + wr * 64 + m * 16 + rg + r;
          dst[(size_t)row * 512 + col] = f2bf(acc[m][n][r] * al);
        }
      }
  }
}

// ---------------------------------------------------------------------------
// Out-proj GEMM: ypre16[8192,512] (bf16) = Ob @ Wo^T + bo + resid(bf16 Xp).
// 128x64 tiles, grid (8, 64) = 512 blocks (2/CU).
__global__ __launch_bounds__(256) void gemm_out(
    const u16* __restrict__ A, const u16* __restrict__ Bt,
    u16* __restrict__ ypre16, const float* __restrict__ bias,
    const u16* __restrict__ residb) {
  __shared__ __align__(16) u16 As[128 * 64];
  __shared__ __align__(16) u16 Bs[64 * 64];
  const int t = threadIdx.x, lane = t & 63, wave = t >> 6;
  const int bn0 = blockIdx.x * 64, bm0 = blockIdx.y * 128;
  const int wr = wave >> 1, wc = wave & 1;
  const u16* Ag = A + (size_t)bm0 * 512;
  const u16* Bg = Bt + (size_t)bn0 * 512;
  f32x4 acc[4][2] = {};
  for (int kt = 0; kt < 512; kt += 64) {
    __syncthreads();
    stage_rows<32>(Ag + kt, 512, As, wave, lane);
    stage_rows<16>(Bg + kt, 512, Bs, wave, lane);
    __syncthreads();
#pragma unroll
    for (int ks = 0; ks < 2; ++ks) {
      bf16x8 af[4], bfr[2];
#pragma unroll
      for (int m = 0; m < 4; ++m)
        af[m] = frag_read(As, wr * 64 + m * 16 + (lane & 15), ks * 4 + (lane >> 4));
#pragma unroll
      for (int n = 0; n < 2; ++n)
        bfr[n] = frag_read(Bs, wc * 32 + n * 16 + (lane & 15), ks * 4 + (lane >> 4));
#pragma unroll
      for (int m = 0; m < 4; ++m)
#pragma unroll
        for (int n = 0; n < 2; ++n)
          acc[m][n] = mfma16(af[m], bfr[n], acc[m][n]);
    }
  }
  const int cl = lane & 15, rg = (lane >> 4) * 4;
#pragma unroll
  for (int m = 0; m < 4; ++m)
#pragma unroll
    for (int n = 0; n < 2; ++n) {
      const int col = bn0 + wc * 32 + n * 16 + cl;
#pragma unroll
      for (int r = 0; r < 4; ++r) {
        const int row = bm0 + wr * 64 + m * 16 + rg + r;
        const float v = acc[m][n][r] + bias[col] + bf2f(residb[(size_t)row * 512 + col]);
        ypre16[(size_t)row * 512 + col] = f2bf(v);
      }
    }
}

// ---------------------------------------------------------------------------
// Flash attention v5: r3 split-K structure + single-instruction exp2 + setprio.
// Grid 1024; wg -> b = wg&7 (XCD-resident K/V), h = (wg>>3)&7, qt = wg>>6.
// Block = 4 waves: qsub = wave&1 (32 q-rows each), half = wave>>1 (kv tiles
// half*8 .. half*8+7). Single-buffered K/V per half (32KB LDS).
// Swapped-operand 32x32x16 MFMA, in-register softmax (exp2 via v_exp_f32,
// Q prescaled by log2e/sqrt(dk)), cvt_pk + permlane32_swap, defer-max.
__global__ __launch_bounds__(256, 4) void attn(
    const u16* __restrict__ Qb, const u16* __restrict__ Kb,
    const u16* __restrict__ Vt, u16* __restrict__ Ob) {
  __shared__ __align__(16) u16 Ks[2][64 * 64];
  __shared__ __align__(16) u16 Vs[2][64 * 64];
  const int t = threadIdx.x, lane = t & 63, wave = t >> 6;
  const int wg = blockIdx.x;
  const int b = wg & 7, h = (wg >> 3) & 7, qt = wg >> 6;
  const int qsub = wave & 1, half = wave >> 1;
  const int ql = lane & 31, hl = lane >> 5;
  const int q0 = qt * 64 + qsub * 32;
  // Q B-fragments straight from global: B[col=q][k=d]
  bf16x8 bq[4];
  {
    const u16* qrow = Qb + ((size_t)b * 1024 + q0 + ql) * 512 + h * 64 + hl * 8;
#pragma unroll
    for (int c = 0; c < 4; ++c) bq[c] = *(const bf16x8*)(qrow + c * 16);
  }
  f32x16 ot[2] = {};
  float m_run = -1e30f, l_run = 0.f;
  // this wave's staging duty: wave&1 stages V[half], else K[half]
  u16* stg_dst = qsub ? Vs[half] : Ks[half];
  for (int i = 0; i < 8; ++i) {
    const int kb = half * 512 + i * 64;   // k-offset of this half's tile i
    {
      const int r_in = lane >> 3, slot = lane & 7;
      const u16* src; size_t gs;
      if (qsub) { src = Vt + (size_t)(h * 64) * 8192 + (size_t)b * 1024 + kb; gs = 8192; }
      else      { src = Kb + ((size_t)b * 1024 + kb) * 512 + h * 64;          gs = 512; }
#pragma unroll
      for (int j = 0; j < 8; ++j) {
        const int row = j * 8 + r_in;
        const int ss = slot ^ (row & 7);
        gl2lds16(src + (size_t)row * gs + ss * 8, stg_dst + j * 512);
      }
    }
    __syncthreads();
    // S^T[k][q] = K[k][:] . Q[q][:]
    f32x16 st[2] = {};
    __builtin_amdgcn_s_setprio(1);
#pragma unroll
    for (int c = 0; c < 4; ++c) {
      bf16x8 a0 = frag_read(Ks[half], ql, c * 2 + hl);
      bf16x8 a1 = frag_read(Ks[half], 32 + ql, c * 2 + hl);
      st[0] = mfma32(a0, bq[c], st[0]);
      st[1] = mfma32(a1, bq[c], st[1]);
    }
    __builtin_amdgcn_s_setprio(0);
    // ---- online softmax with defer-max
    float m0[8];
#pragma unroll
    for (int i2 = 0; i2 < 8; ++i2)
      m0[i2] = fmaxf(fmaxf(st[0][i2], st[0][i2 + 8]), fmaxf(st[1][i2], st[1][i2 + 8]));
#pragma unroll
    for (int i2 = 0; i2 < 4; ++i2) m0[i2] = fmaxf(m0[i2], m0[i2 + 4]);
    float mx = fmaxf(fmaxf(m0[0], m0[1]), fmaxf(m0[2], m0[3]));
    mx = fmaxf(mx, __shfl_xor(mx, 32));
    if (!__all(mx <= m_run + 8.f)) {
      const float mn = fmaxf(m_run, mx);
      const float sc = fexp2(m_run - mn);
      m_run = mn;
      l_run *= sc;
      ot[0] *= sc;
      ot[1] *= sc;
    }
#pragma unroll
    for (int i2 = 0; i2 < 16; ++i2) {
      st[0][i2] = fexp2(st[0][i2] - m_run);
      st[1][i2] = fexp2(st[1][i2] - m_run);
    }
    float s0[8];
#pragma unroll
    for (int i2 = 0; i2 < 8; ++i2)
      s0[i2] = (st[0][i2] + st[0][i2 + 8]) + (st[1][i2] + st[1][i2 + 8]);
#pragma unroll
    for (int i2 = 0; i2 < 4; ++i2) s0[i2] = s0[i2] + s0[i2 + 4];
    float rs = (s0[0] + s0[1]) + (s0[2] + s0[3]);
    rs += __shfl_xor(rs, 32);
    l_run += rs;
    // ---- pack P -> bf16, redistribute, accumulate O^T += V^T P^T
    __builtin_amdgcn_s_setprio(1);
#pragma unroll
    for (int c = 0; c < 4; ++c) {
      const int kf = c >> 1, i0 = (c & 1) * 4;
      u32 w0 = cvt_pk_bf16(st[kf][2 * i0 + 0], st[kf][2 * i0 + 1]);
      u32 w1 = cvt_pk_bf16(st[kf][2 * i0 + 2], st[kf][2 * i0 + 3]);
      u32 w2 = cvt_pk_bf16(st[kf][2 * i0 + 4], st[kf][2 * i0 + 5]);
      u32 w3 = cvt_pk_bf16(st[kf][2 * i0 + 6], st[kf][2 * i0 + 7]);
      perm32swap(w0, w2);
      perm32swap(w1, w3);
      u32x4 wv; wv.x = w0; wv.y = w1; wv.z = w2; wv.w = w3;
      bf16x8 bp = *(bf16x8*)&wv;
      bf16x8 v0 = frag_read(Vs[half], ql, c * 2 + hl);
      bf16x8 v1 = frag_read(Vs[half], 32 + ql, c * 2 + hl);
      ot[0] = mfma32(v0, bp, ot[0]);
      ot[1] = mfma32(v1, bp, ot[1]);
    }
    __builtin_amdgcn_s_setprio(0);
    __syncthreads();
  }
  // ---- merge the two kv-halves (flash-decoding style) through LDS
  float* Om = (float*)&Ks[0][0] + qsub * 2048;   // [64 d][32 q] per qsub
  float* Ml = (float*)&Vs[0][0];                 // m,l per qsub
  if (wave >= 2) {
#pragma unroll
    for (int df = 0; df < 2; ++df)
#pragma unroll
      for (int r = 0; r < 16; ++r) {
        const int dr = (r & 3) + 8 * (r >> 2) + 4 * hl;
        Om[(df * 32 + dr) * 32 + ql] = ot[df][r];
      }
    if (hl == 0) {
      Ml[qsub * 64 + ql] = m_run;
      Ml[qsub * 64 + 32 + ql] = l_run;
    }
    __syncthreads();
  } else {
    __syncthreads();
    const float m2 = Ml[qsub * 64 + ql];
    const float l2 = Ml[qsub * 64 + 32 + ql];
    const float m = fmaxf(m_run, m2);
    const float a = fexp2(m_run - m);
    const float bsc = fexp2(m2 - m);
    const float inv = 1.f / (l_run * a + l2 * bsc);
    u16* orow = Ob + ((size_t)b * 1024 + q0 + ql) * 512 + h * 64;
#pragma unroll
    for (int df = 0; df < 2; ++df)
#pragma unroll
      for (int r = 0; r < 16; ++r) {
        const int dr = (r & 3) + 8 * (r >> 2) + 4 * hl;
        const float v = ot[df][r] * a + Om[(df * 32 + dr) * 32 + ql] * bsc;
        orow[df * 32 + dr] = f2bf(v * inv);
      }
  }
}

// ---------------------------------------------------------------------------
// Single-pass LayerNorm over d=512 (bf16 in) + transpose to (B,C,H,W) fp32.
// grid (64 s-tiles of 16, 8 b), block 256.
__global__ __launch_bounds__(256) void ln_out(
    const u16* __restrict__ ypre16, const float* __restrict__ gamma,
    const float* __restrict__ beta, float* __restrict__ out) {
  __shared__ float tile[16 * 513];
  __shared__ float stats[16][2];
  const int b = blockIdx.y, s0 = blockIdx.x * 16;
  const int t = threadIdx.x, lane = t & 63, wave = t >> 6;
  const u16* src = ypre16 + ((size_t)b * 1024 + s0) * 512;
#pragma unroll
  for (int i = 0; i < 8; ++i) {
    const int idx = i * 256 + t;            // 2048 u16x4 total
    const int flat = idx * 4;
    const int row = flat >> 9, col = flat & 511;
    const u16x4 v = *(const u16x4*)(src + flat);
    float* d = tile + row * 513 + col;
    d[0] = bf2f(v.x); d[1] = bf2f(v.y); d[2] = bf2f(v.z); d[3] = bf2f(v.w);
  }
  __syncthreads();
#pragma unroll
  for (int i = 0; i < 4; ++i) {
    const int r = wave * 4 + i;
    float sum = 0.f, sq = 0.f;
#pragma unroll
    for (int k = 0; k < 8; ++k) {
      const float v = tile[r * 513 + lane + 64 * k];
      sum += v; sq += v * v;
    }
#pragma unroll
    for (int off = 32; off >= 1; off >>= 1) {
      sum += __shfl_xor(sum, off);
      sq  += __shfl_xor(sq, off);
    }
    if (lane == 0) {
      const float mean = sum * (1.f / 512.f);
      const float var = sq * (1.f / 512.f) - mean * mean;
      stats[r][0] = mean;
      stats[r][1] = rsqrtf(var + 1e-5f);
    }
  }
  __syncthreads();
  const int sl = t & 15, cg = t >> 4;
  float* outb = out + (size_t)b * 512 * 1024 + s0;
  const float mean = stats[sl][0], rstd = stats[sl][1];
#pragma unroll 4
  for (int i = 0; i < 32; ++i) {
    const int c = i * 16 + cg;
    const float v = (tile[sl * 513 + c] - mean) * rstd;
    outb[(size_t)c * 1024 + sl] = v * gamma[c] + beta[c];
  }
}

// ---------------------------------------------------------------------------
extern "C" void kernel_launch(void* const* d_in, const int* in_sizes, int n_in,
                              void* d_out, int out_size, void* d_ws, size_t ws_size,
                              hipStream_t stream) {
  const float* x     = (const float*)d_in[0];
  const float* Wq    = (const float*)d_in[1];
  const float* Wk    = (const float*)d_in[2];
  const float* Wv    = (const float*)d_in[3];
  const float* Wo    = (const float*)d_in[4];
  const float* bo    = (const float*)d_in[5];
  const float* gamma = (const float*)d_in[6];
  const float* beta  = (const float*)d_in[7];
  char* ws = (char*)d_ws;
  const size_t MB = 1048576;
  u16*   Xp    = (u16*)(ws);             //  8 MB bf16 (8192,512): x + PE (also residual)
  u16*   Wb    = (u16*)(ws + 8 * MB);    //  2 MB bf16 weights [q][k][v][o]
  u16*   Qb    = (u16*)(ws + 10 * MB);   //  8 MB
  u16*   Kb    = (u16*)(ws + 18 * MB);   //  8 MB
  u16*   Vtb   = (u16*)(ws + 26 * MB);   //  8 MB bf16 V^T (512, 8192)
  u16*   Ob    = (u16*)(ws + 34 * MB);   //  8 MB attention out
  u16*   ypre  = (u16*)(ws + 42 * MB);   //  8 MB bf16 pre-LN

  convert_w<<<dim3(256, 4), 256, 0, stream>>>(Wq, Wk, Wv, Wo, Wb);
  prep_x<<<dim3(32, 16, 8), 256, 0, stream>>>(x, Xp);
  // fused QKV: Q scaled by (1/sqrt(dk))*log2(e); V written transposed
  gemm_qkv<<<dim3(12, 64), 256, 0, stream>>>(Xp, Wb, Qb, Kb, Vtb,
                                             0.125f * 1.44269504088896f);
  attn<<<1024, 256, 0, stream>>>(Qb, Kb, Vtb, Ob);
  gemm_out<<<dim3(8, 64), 256, 0, stream>>>(Ob, Wb + 3 * 262144, ypre, bo, Xp);
  ln_out<<<dim3(64, 8), 256, 0, stream>>>(ypre, gamma, beta, (float*)d_out);
}